// Round 9
// baseline (559.904 us; speedup 1.0000x reference)
//
#include <hip/hip_runtime.h>
#include <math.h>

// Shapes fixed by the reference: B=2, N=32, L=4, ED=64, H=4, HD=16
#define EPS 1e-5f

#define AG_LOAD(p)     __hip_atomic_load((p), __ATOMIC_RELAXED, __HIP_MEMORY_SCOPE_AGENT)

// Order-preserving float<->uint encoding for atomicMax-based float max.
__device__ __forceinline__ unsigned fenc(float f) {
    unsigned u = __float_as_uint(f);
    return (u & 0x80000000u) ? ~u : (u | 0x80000000u);
}
__device__ __forceinline__ float fdec(unsigned u) {
    u = (u & 0x80000000u) ? (u & 0x7FFFFFFFu) : ~u;
    return __uint_as_float(u);
}

struct Params {
    const int* ei; const int* batch; int E;
    const float* W0; const float* b0; const float* Ws; const float* bs;
    const float* ln_g; const float* ln_b;
    const float* fW0; const float* fb0; const float* fWs; const float* fbs;
    const float* fln_g; const float* fln_b;
    const float* opW; const float* opb;
    float* hA; float* hAT;   // h[b][x][a][c] + transposed hT[b][y][x][c], layer 2->3
    float* hB; float* hBT;   // layer 1->2
    float* xbuf;             // x rows, block-owned
    unsigned* PdgU; unsigned* PoffU; unsigned* PmnU;  // [4 layers][2 graphs][64] encoded
    int* bar;                // tail counter (memset 0 each replay)
    float* out;              // 64
};

// Block tiling: 512 blocks x 256 threads; block owns a 2x * 2y row tile.
// blk = b*256 + xgrp*16 + ygrp; x0 = 2*xgrp, y0 = 2*ygrp.
// Thread: rl = tid>>6, rx=rl>>1, ry=rl&1, c = tid&63 (a_l=c&31, h1=c>>5).

__device__ __forceinline__ void pool_atomic(Params& p, int layer, int b_blk, int e,
                                            float mn, float off, float dg) {
    int o = layer * 128 + b_blk * 64 + e;
    atomicMax(&p.PdgU[o],  fenc(dg));
    atomicMax(&p.PoffU[o], fenc(off));
    atomicMax(&p.PmnU[o],  fenc(-mn));
}

// ---------------------------------------------------------------------------
// K1: FUSED layer0 + layer1. Each block recomputes the h1 slabs it needs from
// the 4KB adjacency (layer-0 is closed form) -> no k0 dispatch, no h1 exchange.
__launch_bounds__(256, 2)
__global__ void k1(Params p) {
    const int tid  = threadIdx.x;
    const int blk  = blockIdx.x;
    const int gtid = blk * 256 + tid;
    const int c    = tid & 63;
    const int d    = c & 15;
    const int rl   = tid >> 6;
    const int rx   = rl >> 1;
    const int ry   = rl & 1;
    const int b_blk = blk >> 8;
    const int x0    = ((blk >> 4) & 15) * 2;
    const int y0    = (blk & 15) * 2;
    const int a_l  = c & 31;
    const int h1   = c >> 5;

    __shared__ float adjm[32 * 33];                 // adj[b][x][a], stride 33
    __shared__ __align__(16) float slabX[2][2176];  // h1[x0+i][a][c] rotated
    __shared__ __align__(16) float slabY[2][2176];  // h1[a][y0+j][c] rotated
    __shared__ __align__(16) float WB[8704];        // T65 | ST0 -> FT -> ST1
    __shared__ __align__(16) float cA[64], cC[64], cW[64], cB0[64], cG[64], cBl[64];
    __shared__ float hstat[3][4];
    __shared__ float Wf0[64];
    __shared__ float A1_s[4 * 132];
    __shared__ float K0h_s[4][4];
    __shared__ __align__(16) float xrow[4][64];
    __shared__ __align__(16) float xu_s[4][64];
    __shared__ __align__(16) float g16[16], b16[16];

    // ---- init: consts, weights, adj zero ----
    for (int i = tid; i < 1056; i += 256) adjm[i] = 0.0f;
    if (tid < 64) {
        float Wc = p.W0[c], bc = p.b0[c];
        float sW = Wc, sB = bc;
        #pragma unroll
        for (int m = 1; m < 16; m <<= 1) {
            sW += __shfl_xor(sW, m, 16);
            sB += __shfl_xor(sB, m, 16);
        }
        float Ac = Wc - sW * 0.0625f;
        float Bc = bc - sB * 0.0625f;
        float sAA = Ac * Ac, sAB = Ac * Bc, sBB = Bc * Bc;
        #pragma unroll
        for (int m = 1; m < 16; m <<= 1) {
            sAA += __shfl_xor(sAA, m, 16);
            sAB += __shfl_xor(sAB, m, 16);
            sBB += __shfl_xor(sBB, m, 16);
        }
        cA[c] = Ac; cC[c] = Bc; cW[c] = Wc; cB0[c] = bc;
        cG[c] = p.ln_g[d]; cBl[c] = p.ln_b[d];
        if (d == 0) {
            hstat[0][c >> 4] = sAA * 0.0625f;
            hstat[1][c >> 4] = sAB * 0.0625f;
            hstat[2][c >> 4] = sBB * 0.0625f;
        }
        Wf0[tid] = p.fW0[tid * 65];
    }
    if (tid < 16) {
        g16[tid] = p.ln_g[16 + tid];    // layer-1 LN16 params
        b16[tid] = p.ln_b[16 + tid];
    }
    #pragma unroll
    for (int s = 0; s < 4; ++s) {       // T65 = fW0[:,1:65], stride 68
        int i = tid + s * 256;
        int cc = i >> 4, u = i & 15;
        const float* src = p.fW0 + cc * 65 + 1 + 4 * u;
        float4 w = make_float4(src[0], src[1], src[2], src[3]);
        *(float4*)(WB + cc * 68 + 4 * ((u + 2 * cc) & 15)) = w;
    }
    #pragma unroll
    for (int s = 0; s < 4; ++s) {       // ST0 = Ws[0], stride 68, base 4352
        int i = tid + s * 256;
        float4 w = ((const float4*)p.Ws)[i];
        int cc = i >> 4, u = i & 15;
        *(float4*)(WB + 4352 + cc * 68 + 4 * ((u + 2 * cc) & 15)) = w;
    }
    __syncthreads();

    // ---- edge scan: full adjacency for this graph ----
    for (int e2 = tid; e2 < p.E; e2 += 256) {
        int e0 = p.ei[e2], e1 = p.ei[p.E + e2];
        int g  = p.batch[e0];
        if (g == b_blk) {
            int ls = e0 - g * 32, ld = e1 - g * 32;
            atomicAdd(&adjm[ls * 33 + ld], 1.0f);
        }
    }
    __syncthreads();
    if (tid < 32) adjm[tid * 33 + tid] = 2.0f;
    __syncthreads();

    // ======== phase A: compute h1 slabs locally (32 rows per wave) ========
    #pragma unroll 1
    for (int k = 0; k < 32; ++k) {
        const int r = rl * 32 + k;
        const bool isX = (r < 64);
        const int rowx = isX ? (x0 + (r >> 5)) : ((r - 64) >> 1);
        const int coly = isX ? (r & 31) : (y0 + ((r - 64) & 1));
        const float vx = adjm[rowx * 33 + a_l];
        const float vy = adjm[a_l * 33 + coly];

        float s0, s1, is0, is1, w0m, w1m;
        #pragma unroll
        for (int hb = 0; hb < 2; ++hb) {
            const int hh = h1 + 2 * hb;
            float rsx = rsqrtf(fmaf(fmaf(hstat[0][hh], vx, 2.0f * hstat[1][hh]), vx, hstat[2][hh]) + EPS);
            float rsy = rsqrtf(fmaf(fmaf(hstat[0][hh], vy, 2.0f * hstat[1][hh]), vy, hstat[2][hh]) + EPS);
            float qq = 0.f, sp = 0.f, sq = 0.f;
            #pragma unroll
            for (int t = 0; t < 4; ++t) {
                int dd = hh * 16 + 4 * t;
                float4 av = *(const float4*)(cA + dd);
                float4 bv = *(const float4*)(cC + dd);
                float4 wv = *(const float4*)(cW + dd);
                float4 b0v = *(const float4*)(cB0 + dd);
                float4 gv = *(const float4*)(cG + dd);
                float4 blv = *(const float4*)(cBl + dd);
                float qx, qy, pp;
                qx = fmaf(av.x, vx, bv.x) * rsx * gv.x + blv.x;
                qy = fmaf(av.x, vy, bv.x) * rsy * gv.x + blv.x;
                qq = fmaf(qx, qy, qq);
                pp = fmaf(wv.x, vx, b0v.x) * fmaf(wv.x, vy, b0v.x); sp += pp; sq += pp * pp;
                qx = fmaf(av.y, vx, bv.y) * rsx * gv.y + blv.y;
                qy = fmaf(av.y, vy, bv.y) * rsy * gv.y + blv.y;
                qq = fmaf(qx, qy, qq);
                pp = fmaf(wv.y, vx, b0v.y) * fmaf(wv.y, vy, b0v.y); sp += pp; sq += pp * pp;
                qx = fmaf(av.z, vx, bv.z) * rsx * gv.z + blv.z;
                qy = fmaf(av.z, vy, bv.z) * rsy * gv.z + blv.z;
                qq = fmaf(qx, qy, qq);
                pp = fmaf(wv.z, vx, b0v.z) * fmaf(wv.z, vy, b0v.z); sp += pp; sq += pp * pp;
                qx = fmaf(av.w, vx, bv.w) * rsx * gv.w + blv.w;
                qy = fmaf(av.w, vy, bv.w) * rsy * gv.w + blv.w;
                qq = fmaf(qx, qy, qq);
                pp = fmaf(wv.w, vx, b0v.w) * fmaf(wv.w, vy, b0v.w); sp += pp; sq += pp * pp;
            }
            float ss = qq * 0.25f;
            float mu = sp * 0.0625f, var = fmaxf(sq * 0.0625f - mu * mu, 0.f);
            float is = rsqrtf(var + EPS);
            if (hb == 0) { s0 = ss; is0 = is; w0m = mu * is; }
            else         { s1 = ss; is1 = is; w1m = mu * is; }
        }

        float m0 = s0, m1 = s1;
        #pragma unroll
        for (int m = 1; m < 32; m <<= 1) {
            m0 = fmaxf(m0, __shfl_xor(m0, m));
            m1 = fmaxf(m1, __shfl_xor(m1, m));
        }
        float e0 = __expf(s0 - m0), e1 = __expf(s1 - m1);
        float l0 = e0, l1 = e1, k0a = e0 * w0m, k1a = e1 * w1m;
        #pragma unroll
        for (int m = 1; m < 32; m <<= 1) {
            l0 += __shfl_xor(l0, m);  l1 += __shfl_xor(l1, m);
            k0a += __shfl_xor(k0a, m); k1a += __shfl_xor(k1a, m);
        }
        A1_s[rl * 132 + h1 * 33 + a_l]       = e0 * is0 / l0;
        A1_s[rl * 132 + (h1 + 2) * 33 + a_l] = e1 * is1 / l1;
        if (a_l == 0) {
            K0h_s[rl][h1]     = k0a / l0;
            K0h_s[rl][h1 + 2] = k1a / l1;
        }

        // pass2 from adj scalars
        {
            const int hc = c >> 4;
            const float Wc = cW[c], bc = cB0[c];
            float accp = 0.f;
            #pragma unroll
            for (int a = 0; a < 32; ++a) {
                float vx2 = adjm[rowx * 33 + a];
                float vy2 = adjm[a * 33 + coly];
                float pv = fmaf(Wc, vx2, bc) * fmaf(Wc, vy2, bc);
                accp = fmaf(A1_s[rl * 132 + hc * 33 + a], pv, accp);
            }
            xu_s[rl][c] = (accp - K0h_s[rl][hc]) * cG[c] + cBl[c];
        }

        // fin (K=65) + LN64 -> x1
        const float adjv = adjm[rowx * 33 + coly];
        float acc2 = fmaf(Wf0[c], adjv, p.fb0[c]);
        #pragma unroll
        for (int u = 0; u < 16; ++u) {
            float4 w = *(const float4*)(WB + c * 68 + 4 * ((u + 2 * c) & 15));
            float4 xr = *(const float4*)(&xu_s[rl][4 * u]);
            acc2 = fmaf(w.x, xr.x, acc2); acc2 = fmaf(w.y, xr.y, acc2);
            acc2 = fmaf(w.z, xr.z, acc2); acc2 = fmaf(w.w, xr.w, acc2);
        }
        float t1 = acc2;
        #pragma unroll
        for (int m = 1; m < 64; m <<= 1) t1 += __shfl_xor(t1, m, 64);
        float mu = t1 * (1.0f / 64.0f);
        float dv2 = acc2 - mu;
        float t2 = dv2 * dv2;
        #pragma unroll
        for (int m = 1; m < 64; m <<= 1) t2 += __shfl_xor(t2, m, 64);
        float x1c = dv2 * rsqrtf(t2 * (1.0f / 64.0f) + EPS) * p.fln_g[c] + p.fln_b[c];

        if (isX && (unsigned)(coly - y0) < 2u)
            xrow[(rowx - x0) * 2 + (coly - y0)][c] = x1c;   // own rows' x1
        xu_s[rl][c] = x1c;                                  // broadcast row for lin

        // lin: h1 = x1 @ Ws[0].T + bs[0]  (ST0 at WB+4352)
        float acch = p.bs[c];
        #pragma unroll
        for (int u = 0; u < 16; ++u) {
            float4 w = *(const float4*)(WB + 4352 + c * 68 + 4 * ((u + 2 * c) & 15));
            float4 xr = *(const float4*)(&xu_s[rl][4 * u]);
            acch = fmaf(w.x, xr.x, acch); acch = fmaf(w.y, xr.y, acch);
            acch = fmaf(w.z, xr.z, acch); acch = fmaf(w.w, xr.w, acch);
        }
        float* srow = isX ? &slabX[r >> 5][0] : &slabY[(r - 64) & 1][0];
        const int arow = isX ? (r & 31) : ((r - 64) >> 1);
        srow[arow * 68 + 4 * (((c >> 2) + 2 * arow) & 15) + (c & 3)] = acch;
    }
    __syncthreads();

    // pool layer 0 (own rows' x1 in xrow)
    if (tid < 64) {
        float mn = 1e30f, off = -1e30f, dg = -1e30f;
        #pragma unroll
        for (int r2 = 0; r2 < 4; ++r2) {
            float v = xrow[r2][tid];
            mn = fminf(mn, v);
            if (x0 + (r2 >> 1) == y0 + (r2 & 1)) dg = fmaxf(dg, v);
            else off = fmaxf(off, v);
        }
        pool_atomic(p, 0, b_blk, tid, mn, off, dg);
    }
    // stage FT = fWs[0] into WB (stride 132)
    {
        const float4* fw = (const float4*)(p.fWs);
        #pragma unroll
        for (int s = 0; s < 8; ++s) {
            int i = tid + s * 256;
            float4 w = fw[i];
            int cc = i >> 5, u = i & 31;
            *(float4*)(WB + cc * 132 + 4 * ((u + 2 * cc) & 31)) = w;
        }
    }
    __syncthreads();

    // ======== phase B: layer-1 attention body (slabs in LDS) ========
    float s0, s1, is0, is1, w0m, w1m;
    #pragma unroll
    for (int hb = 0; hb < 2; ++hb) {
        const int hh = h1 + 2 * hb;
        float4 xh4[4], yh4[4];
        float sxp = 0.f, sxq = 0.f, syp = 0.f, syq = 0.f;
        #pragma unroll
        for (int t = 0; t < 4; ++t) {
            int ps = 4 * (((hh * 4 + t) + 2 * a_l) & 15);
            float4 v = *(const float4*)(&slabX[rx][a_l * 68 + ps]);
            float4 y = *(const float4*)(&slabY[ry][a_l * 68 + ps]);
            xh4[t] = v; yh4[t] = y;
            sxp += v.x + v.y + v.z + v.w;
            sxq += v.x*v.x + v.y*v.y + v.z*v.z + v.w*v.w;
            syp += y.x + y.y + y.z + y.w;
            syq += y.x*y.x + y.y*y.y + y.z*y.z + y.w*y.w;
        }
        float mxm = sxp * 0.0625f;
        float rsx = rsqrtf(fmaxf(sxq * 0.0625f - mxm * mxm, 0.f) + EPS);
        float mym = syp * 0.0625f;
        float rsy = rsqrtf(fmaxf(syq * 0.0625f - mym * mym, 0.f) + EPS);
        float qq = 0.f, sp = 0.f, sq = 0.f;
        #pragma unroll
        for (int t = 0; t < 4; ++t) {
            float4 g4 = *(const float4*)(g16 + 4 * t);
            float4 b4 = *(const float4*)(b16 + 4 * t);
            float4 xh = xh4[t], yh = yh4[t];
            float qx, qy, pp;
            qx = (xh.x - mxm) * rsx * g4.x + b4.x;
            qy = (yh.x - mym) * rsy * g4.x + b4.x;
            qq = fmaf(qx, qy, qq);  pp = xh.x * yh.x; sp += pp; sq += pp * pp;
            qx = (xh.y - mxm) * rsx * g4.y + b4.y;
            qy = (yh.y - mym) * rsy * g4.y + b4.y;
            qq = fmaf(qx, qy, qq);  pp = xh.y * yh.y; sp += pp; sq += pp * pp;
            qx = (xh.z - mxm) * rsx * g4.z + b4.z;
            qy = (yh.z - mym) * rsy * g4.z + b4.z;
            qq = fmaf(qx, qy, qq);  pp = xh.z * yh.z; sp += pp; sq += pp * pp;
            qx = (xh.w - mxm) * rsx * g4.w + b4.w;
            qy = (yh.w - mym) * rsy * g4.w + b4.w;
            qq = fmaf(qx, qy, qq);  pp = xh.w * yh.w; sp += pp; sq += pp * pp;
        }
        float ss = qq * 0.25f;
        float mu = sp * 0.0625f, var = fmaxf(sq * 0.0625f - mu * mu, 0.f);
        float is = rsqrtf(var + EPS);
        if (hb == 0) { s0 = ss; is0 = is; w0m = mu * is; }
        else         { s1 = ss; is1 = is; w1m = mu * is; }
    }
    float m0 = s0, m1 = s1;
    #pragma unroll
    for (int m = 1; m < 32; m <<= 1) {
        m0 = fmaxf(m0, __shfl_xor(m0, m));
        m1 = fmaxf(m1, __shfl_xor(m1, m));
    }
    float e0 = __expf(s0 - m0), e1 = __expf(s1 - m1);
    float l0 = e0, l1 = e1, k0a = e0 * w0m, k1a = e1 * w1m;
    #pragma unroll
    for (int m = 1; m < 32; m <<= 1) {
        l0 += __shfl_xor(l0, m);  l1 += __shfl_xor(l1, m);
        k0a += __shfl_xor(k0a, m); k1a += __shfl_xor(k1a, m);
    }
    A1_s[rl * 132 + h1 * 33 + a_l]       = e0 * is0 / l0;
    A1_s[rl * 132 + (h1 + 2) * 33 + a_l] = e1 * is1 / l1;
    if (a_l == 0) {
        K0h_s[rl][h1]     = k0a / l0;
        K0h_s[rl][h1 + 2] = k1a / l1;
    }
    {
        const int hc = c >> 4;
        const int ce = c & 3;
        float acc = 0.f;
        #pragma unroll
        for (int a = 0; a < 32; ++a) {
            int ps = 4 * (((c >> 2) + 2 * a) & 15) + ce;
            float hxv = slabX[rx][a * 68 + ps];
            float hyv = slabY[ry][a * 68 + ps];
            acc = fmaf(A1_s[rl * 132 + hc * 33 + a], hxv * hyv, acc);
        }
        xu_s[rl][c] = (acc - K0h_s[rl][hc]) * g16[d] + b16[d];
    }
    // fin + LN64 (FT in WB, stride 132)
    float acc2 = p.fbs[c];
    #pragma unroll
    for (int u = 0; u < 16; ++u) {
        float4 w = *(const float4*)(WB + c * 132 + 4 * ((u + 2 * c) & 31));
        float4 xr = *(const float4*)(&xrow[rl][4 * u]);
        acc2 = fmaf(w.x, xr.x, acc2); acc2 = fmaf(w.y, xr.y, acc2);
        acc2 = fmaf(w.z, xr.z, acc2); acc2 = fmaf(w.w, xr.w, acc2);
    }
    #pragma unroll
    for (int u = 16; u < 32; ++u) {
        float4 w = *(const float4*)(WB + c * 132 + 4 * ((u + 2 * c) & 31));
        float4 xr = *(const float4*)(&xu_s[rl][4 * (u - 16)]);
        acc2 = fmaf(w.x, xr.x, acc2); acc2 = fmaf(w.y, xr.y, acc2);
        acc2 = fmaf(w.z, xr.z, acc2); acc2 = fmaf(w.w, xr.w, acc2);
    }
    float t1 = acc2;
    #pragma unroll
    for (int m = 1; m < 64; m <<= 1) t1 += __shfl_xor(t1, m, 64);
    float mu = t1 * (1.0f / 64.0f);
    float dv2 = acc2 - mu;
    float t2 = dv2 * dv2;
    #pragma unroll
    for (int m = 1; m < 64; m <<= 1) t2 += __shfl_xor(t2, m, 64);
    float xnew = dv2 * rsqrtf(t2 * (1.0f / 64.0f) + EPS) *
                 p.fln_g[64 + c] + p.fln_b[64 + c];
    __syncthreads();
    xrow[rl][c] = xnew;
    p.xbuf[gtid] = xnew;
    // restage ST1 = Ws[1] into WB (stride 68)
    {
        const float4* sw = (const float4*)(p.Ws + 4096);
        #pragma unroll
        for (int s = 0; s < 4; ++s) {
            int i = tid + s * 256;
            float4 w = sw[i];
            int cc = i >> 4, u = i & 15;
            *(float4*)(WB + cc * 68 + 4 * ((u + 2 * cc) & 15)) = w;
        }
    }
    __syncthreads();

    if (tid < 64) {
        float mn = 1e30f, off = -1e30f, dg = -1e30f;
        #pragma unroll
        for (int r2 = 0; r2 < 4; ++r2) {
            float v = xrow[r2][tid];
            mn = fminf(mn, v);
            if (x0 + (r2 >> 1) == y0 + (r2 & 1)) dg = fmaxf(dg, v);
            else off = fmaxf(off, v);
        }
        pool_atomic(p, 1, b_blk, tid, mn, off, dg);
    }
    {
        float acc = p.bs[64 + c];
        #pragma unroll
        for (int u = 0; u < 16; ++u) {
            float4 w = *(const float4*)(WB + c * 68 + 4 * ((u + 2 * c) & 15));
            float4 xr = *(const float4*)(&xrow[rl][4 * u]);
            acc = fmaf(w.x, xr.x, acc); acc = fmaf(w.y, xr.y, acc);
            acc = fmaf(w.z, xr.z, acc); acc = fmaf(w.w, xr.w, acc);
        }
        int x = x0 + rx, y = y0 + ry;
        p.hB[(b_blk * 1024 + x * 32 + y) * 64 + c] = acc;
        p.hBT[((b_blk * 32 + y) * 32 + x) * 64 + c] = acc;
    }
}

// ---------------------------------------------------------------------------
__launch_bounds__(256, 2)
__global__ void klayer(Params p, int layer, int is_last) {
    const int tid  = threadIdx.x;
    const int blk  = blockIdx.x;
    const int gtid = blk * 256 + tid;
    const int c    = tid & 63;
    const int d    = c & 15;
    const int rl   = tid >> 6;
    const int rx   = rl >> 1;
    const int ry   = rl & 1;
    const int b_blk = blk >> 8;
    const int x0    = ((blk >> 4) & 15) * 2;
    const int y0    = (blk & 15) * 2;
    const int a_l  = c & 31;
    const int h1   = c >> 5;

    const float* hin  = (layer == 2) ? p.hB  : p.hA;
    const float* hinT = (layer == 2) ? p.hBT : p.hAT;
    float* hout  = (layer == 1) ? p.hB  : p.hA;
    float* houtT = (layer == 1) ? p.hBT : p.hAT;

    __shared__ __align__(16) float hx2_s[2][2176];
    __shared__ __align__(16) float yT2_s[2][2176];
    __shared__ __align__(16) float FT[64 * 132];
    __shared__ float A1_s[4 * 132];
    __shared__ float K0h_s[4][4];
    __shared__ __align__(16) float xrow[4][64];
    __shared__ __align__(16) float xu_s[4][64];
    __shared__ __align__(16) float g16[16], b16[16];
    __shared__ float vals[4];
    __shared__ float scores_s[64];
    __shared__ int tailflag;
    float* sm_mn  = &hx2_s[0][0];
    float* sm_off = sm_mn + 512;
    float* sm_dg  = sm_mn + 1024;
    float* psum   = sm_mn + 1536;

    float xv = p.xbuf[gtid];
    {
        const float4* sx0 = (const float4*)(hin + (b_blk * 1024 + x0 * 32) * 64);
        const float4* sx1 = (const float4*)(hin + (b_blk * 1024 + (x0 + 1) * 32) * 64);
        const float4* sy0 = (const float4*)(hinT + (b_blk * 32 + y0) * 2048);
        const float4* sy1 = (const float4*)(hinT + (b_blk * 32 + y0 + 1) * 2048);
        #pragma unroll
        for (int s = 0; s < 2; ++s) {
            int ii = tid + s * 256;
            int a = ii >> 4, u = ii & 15, pr = (u + 2 * a) & 15;
            *(float4*)(&hx2_s[0][a * 68 + 4 * pr]) = sx0[ii];
            *(float4*)(&hx2_s[1][a * 68 + 4 * pr]) = sx1[ii];
            *(float4*)(&yT2_s[0][a * 68 + 4 * pr]) = sy0[ii];
            *(float4*)(&yT2_s[1][a * 68 + 4 * pr]) = sy1[ii];
        }
    }
    if (tid < 16) {
        g16[tid] = p.ln_g[layer * 16 + tid];
        b16[tid] = p.ln_b[layer * 16 + tid];
    }
    {
        const float4* fw = (const float4*)(p.fWs + (layer - 1) * 8192);
        #pragma unroll
        for (int s = 0; s < 8; ++s) {
            int i = tid + s * 256;
            float4 w = fw[i];
            int cc = i >> 5, u = i & 31;
            *(float4*)(FT + cc * 132 + 4 * ((u + 2 * cc) & 31)) = w;
        }
    }
    xrow[rl][c] = xv;
    __syncthreads();

    float s0, s1, is0, is1, w0m, w1m;
    #pragma unroll
    for (int hb = 0; hb < 2; ++hb) {
        const int hh = h1 + 2 * hb;
        float4 xh4[4], yh4[4];
        float sxp = 0.f, sxq = 0.f, syp = 0.f, syq = 0.f;
        #pragma unroll
        for (int t = 0; t < 4; ++t) {
            int ps = 4 * (((hh * 4 + t) + 2 * a_l) & 15);
            float4 v = *(const float4*)(&hx2_s[rx][a_l * 68 + ps]);
            float4 y = *(const float4*)(&yT2_s[ry][a_l * 68 + ps]);
            xh4[t] = v; yh4[t] = y;
            sxp += v.x + v.y + v.z + v.w;
            sxq += v.x*v.x + v.y*v.y + v.z*v.z + v.w*v.w;
            syp += y.x + y.y + y.z + y.w;
            syq += y.x*y.x + y.y*y.y + y.z*y.z + y.w*y.w;
        }
        float mxm = sxp * 0.0625f;
        float rsx = rsqrtf(fmaxf(sxq * 0.0625f - mxm * mxm, 0.f) + EPS);
        float mym = syp * 0.0625f;
        float rsy = rsqrtf(fmaxf(syq * 0.0625f - mym * mym, 0.f) + EPS);
        float qq = 0.f, sp = 0.f, sq = 0.f;
        #pragma unroll
        for (int t = 0; t < 4; ++t) {
            float4 g4 = *(const float4*)(g16 + 4 * t);
            float4 b4 = *(const float4*)(b16 + 4 * t);
            float4 xh = xh4[t], yh = yh4[t];
            float qx, qy, pp;
            qx = (xh.x - mxm) * rsx * g4.x + b4.x;
            qy = (yh.x - mym) * rsy * g4.x + b4.x;
            qq = fmaf(qx, qy, qq);  pp = xh.x * yh.x; sp += pp; sq += pp * pp;
            qx = (xh.y - mxm) * rsx * g4.y + b4.y;
            qy = (yh.y - mym) * rsy * g4.y + b4.y;
            qq = fmaf(qx, qy, qq);  pp = xh.y * yh.y; sp += pp; sq += pp * pp;
            qx = (xh.z - mxm) * rsx * g4.z + b4.z;
            qy = (yh.z - mym) * rsy * g4.z + b4.z;
            qq = fmaf(qx, qy, qq);  pp = xh.z * yh.z; sp += pp; sq += pp * pp;
            qx = (xh.w - mxm) * rsx * g4.w + b4.w;
            qy = (yh.w - mym) * rsy * g4.w + b4.w;
            qq = fmaf(qx, qy, qq);  pp = xh.w * yh.w; sp += pp; sq += pp * pp;
        }
        float ss = qq * 0.25f;
        float mu = sp * 0.0625f, var = fmaxf(sq * 0.0625f - mu * mu, 0.f);
        float is = rsqrtf(var + EPS);
        if (hb == 0) { s0 = ss; is0 = is; w0m = mu * is; }
        else         { s1 = ss; is1 = is; w1m = mu * is; }
    }

    float m0 = s0, m1 = s1;
    #pragma unroll
    for (int m = 1; m < 32; m <<= 1) {
        m0 = fmaxf(m0, __shfl_xor(m0, m));
        m1 = fmaxf(m1, __shfl_xor(m1, m));
    }
    float e0 = __expf(s0 - m0), e1 = __expf(s1 - m1);
    float l0 = e0, l1 = e1, k0a = e0 * w0m, k1a = e1 * w1m;
    #pragma unroll
    for (int m = 1; m < 32; m <<= 1) {
        l0 += __shfl_xor(l0, m);  l1 += __shfl_xor(l1, m);
        k0a += __shfl_xor(k0a, m); k1a += __shfl_xor(k1a, m);
    }
    A1_s[rl * 132 + h1 * 33 + a_l]       = e0 * is0 / l0;
    A1_s[rl * 132 + (h1 + 2) * 33 + a_l] = e1 * is1 / l1;
    if (a_l == 0) {
        K0h_s[rl][h1]     = k0a / l0;
        K0h_s[rl][h1 + 2] = k1a / l1;
    }

    {
        const int hc = c >> 4;
        const int ce = c & 3;
        float acc = 0.f;
        #pragma unroll
        for (int a = 0; a < 32; ++a) {
            int ps = 4 * (((c >> 2) + 2 * a) & 15) + ce;
            float hxv = hx2_s[rx][a * 68 + ps];
            float hyv = yT2_s[ry][a * 68 + ps];
            acc = fmaf(A1_s[rl * 132 + hc * 33 + a], hxv * hyv, acc);
        }
        xu_s[rl][c] = (acc - K0h_s[rl][hc]) * g16[d] + b16[d];
    }

    float acc2 = p.fbs[(layer - 1) * 64 + c];
    #pragma unroll
    for (int u = 0; u < 16; ++u) {
        float4 w = *(const float4*)(FT + c * 132 + 4 * ((u + 2 * c) & 31));
        float4 xr = *(const float4*)(&xrow[rl][4 * u]);
        acc2 = fmaf(w.x, xr.x, acc2); acc2 = fmaf(w.y, xr.y, acc2);
        acc2 = fmaf(w.z, xr.z, acc2); acc2 = fmaf(w.w, xr.w, acc2);
    }
    #pragma unroll
    for (int u = 16; u < 32; ++u) {
        float4 w = *(const float4*)(FT + c * 132 + 4 * ((u + 2 * c) & 31));
        float4 xr = *(const float4*)(&xu_s[rl][4 * (u - 16)]);
        acc2 = fmaf(w.x, xr.x, acc2); acc2 = fmaf(w.y, xr.y, acc2);
        acc2 = fmaf(w.z, xr.z, acc2); acc2 = fmaf(w.w, xr.w, acc2);
    }
    float t1 = acc2;
    #pragma unroll
    for (int m = 1; m < 64; m <<= 1) t1 += __shfl_xor(t1, m, 64);
    float mu = t1 * (1.0f / 64.0f);
    float dv2 = acc2 - mu;
    float t2 = dv2 * dv2;
    #pragma unroll
    for (int m = 1; m < 64; m <<= 1) t2 += __shfl_xor(t2, m, 64);
    float xnew = dv2 * rsqrtf(t2 * (1.0f / 64.0f) + EPS) *
                 p.fln_g[layer * 64 + c] + p.fln_b[layer * 64 + c];
    __syncthreads();
    xrow[rl][c] = xnew;
    if (!is_last) {
        p.xbuf[gtid] = xnew;
        const float4* sw = (const float4*)(p.Ws + layer * 4096);
        #pragma unroll
        for (int s = 0; s < 4; ++s) {
            int i = tid + s * 256;
            float4 w = sw[i];
            int cc = i >> 4, u = i & 15;
            *(float4*)(FT + cc * 68 + 4 * ((u + 2 * cc) & 15)) = w;
        }
    }
    __syncthreads();

    if (tid < 64) {
        float mn = 1e30f, off = -1e30f, dg = -1e30f;
        #pragma unroll
        for (int r2 = 0; r2 < 4; ++r2) {
            float v = xrow[r2][tid];
            mn = fminf(mn, v);
            if (x0 + (r2 >> 1) == y0 + (r2 & 1)) dg = fmaxf(dg, v);
            else off = fmaxf(off, v);
        }
        pool_atomic(p, layer, b_blk, tid, mn, off, dg);
    }

    if (!is_last) {
        float acc = p.bs[layer * 64 + c];
        #pragma unroll
        for (int u = 0; u < 16; ++u) {
            float4 w = *(const float4*)(FT + c * 68 + 4 * ((u + 2 * c) & 15));
            float4 xr = *(const float4*)(&xrow[rl][4 * u]);
            acc = fmaf(w.x, xr.x, acc); acc = fmaf(w.y, xr.y, acc);
            acc = fmaf(w.z, xr.z, acc); acc = fmaf(w.w, xr.w, acc);
        }
        int x = x0 + rx, y = y0 + ry;
        hout[(b_blk * 1024 + x * 32 + y) * 64 + c] = acc;
        houtT[((b_blk * 32 + y) * 32 + x) * 64 + c] = acc;
        return;
    }

    __syncthreads();
    if (tid == 0) {
        int r = __hip_atomic_fetch_add(p.bar, 1, __ATOMIC_RELAXED,
                                       __HIP_MEMORY_SCOPE_AGENT);
        tailflag = (r == 511) ? 1 : 0;
    }
    __syncthreads();
    if (!tailflag) return;

    #pragma unroll
    for (int s = 0; s < 2; ++s) {
        int slot = tid + s * 256;
        unsigned ud = AG_LOAD(&p.PdgU[slot]);
        unsigned uo = AG_LOAD(&p.PoffU[slot]);
        unsigned um = AG_LOAD(&p.PmnU[slot]);
        sm_dg[slot]  = fdec(ud);
        sm_off[slot] = fdec(uo);
        sm_mn[slot]  = -fdec(um);
    }
    __syncthreads();
    if (tid < 4) {
        float gmx = -1e30f, gmn = 1e30f;
        for (int i2 = 0; i2 < 128; ++i2) {
            gmx = fmaxf(gmx, sm_dg[tid * 128 + i2]);
            gmn = fminf(gmn, sm_mn[tid * 128 + i2]);
        }
        vals[tid] = fabsf(gmx - gmn);
    }
    __syncthreads();
    {
        int bb = tid >> 7, cc = (tid >> 2) & 31, pp = tid & 3;
        float a2 = 0.0f;
        for (int l = 0; l < 4; ++l) {
            float val = vals[l];
            const float* Wr = p.opW + l * 4096 + cc * 128;
            int base = l * 128 + bb * 64;
            for (int j = pp * 32; j < pp * 32 + 32; ++j) {
                float pv;
                if (j < 64) pv = sm_dg[base + j];
                else        pv = fmaxf(sm_off[base + j - 64], sm_dg[base + j - 64] - val);
                a2 = fmaf(Wr[j], pv, a2);
            }
        }
        psum[tid] = a2;
    }
    __syncthreads();
    if (tid < 64) {
        int bb = tid >> 5, cc = tid & 31;
        float a2 = 0.0f;
        for (int l = 0; l < 4; ++l) a2 += p.opb[l * 32 + cc];
        for (int pp = 0; pp < 4; ++pp) a2 += psum[bb * 128 + cc * 4 + pp];
        scores_s[tid] = a2;
    }
    __syncthreads();
    if (tid < 32) {
        float sA = scores_s[tid], sB = scores_s[32 + tid];
        float mu2 = 0.5f * (sA + sB);
        float va = 0.5f * ((sA - mu2) * (sA - mu2) + (sB - mu2) * (sB - mu2));
        float inv = rsqrtf(va + EPS);
        p.out[tid]      = (sA - mu2) * inv;
        p.out[32 + tid] = (sB - mu2) * inv;
    }
}

// ---------------------------------------------------------------------------
extern "C" void kernel_launch(void* const* d_in, const int* in_sizes, int n_in,
                              void* d_out, int out_size, void* d_ws, size_t ws_size,
                              hipStream_t stream) {
    Params prm;
    prm.ei    = (const int*)d_in[0];
    prm.batch = (const int*)d_in[1];
    prm.E     = in_sizes[0] / 2;
    prm.W0    = (const float*)d_in[2];
    prm.b0    = (const float*)d_in[3];
    prm.Ws    = (const float*)d_in[4];
    prm.bs    = (const float*)d_in[5];
    prm.ln_g  = (const float*)d_in[6];
    prm.ln_b  = (const float*)d_in[7];
    prm.fW0   = (const float*)d_in[8];
    prm.fb0   = (const float*)d_in[9];
    prm.fWs   = (const float*)d_in[10];
    prm.fbs   = (const float*)d_in[11];
    prm.fln_g = (const float*)d_in[12];
    prm.fln_b = (const float*)d_in[13];
    prm.opW   = (const float*)d_in[14];
    prm.opb   = (const float*)d_in[15];

    float* ws = (float*)d_ws;
    prm.hA    = ws;
    prm.hAT   = prm.hA   + 131072;
    prm.hB    = prm.hAT  + 131072;
    prm.hBT   = prm.hB   + 131072;
    prm.xbuf  = prm.hBT  + 131072;
    unsigned* pu = (unsigned*)(prm.xbuf + 131072);
    prm.PdgU  = pu;
    prm.PoffU = pu + 512;
    prm.PmnU  = pu + 1024;
    prm.bar   = (int*)(pu + 1536);
    prm.out   = (float*)d_out;

    hipMemsetAsync(pu, 0, 1552 * sizeof(unsigned), stream);
    k1<<<512, 256, 0, stream>>>(prm);
    klayer<<<512, 256, 0, stream>>>(prm, 2, 0);
    klayer<<<512, 256, 0, stream>>>(prm, 3, 1);
}

// Round 10
// 169.603 us; speedup vs baseline: 3.3013x; 3.3013x over previous
//
#include <hip/hip_runtime.h>
#include <math.h>

// Shapes fixed by the reference: B=2, N=32, L=4, ED=64, H=4, HD=16
#define EPS 1e-5f

#define AG_LOAD(p)     __hip_atomic_load((p), __ATOMIC_RELAXED, __HIP_MEMORY_SCOPE_AGENT)
#define AG_STORE(p, v) __hip_atomic_store((p), (v), __ATOMIC_RELAXED, __HIP_MEMORY_SCOPE_AGENT)

// Order-preserving float<->uint encoding for atomicMax-based float max.
__device__ __forceinline__ unsigned fenc(float f) {
    unsigned u = __float_as_uint(f);
    return (u & 0x80000000u) ? ~u : (u | 0x80000000u);
}
__device__ __forceinline__ float fdec(unsigned u) {
    u = (u & 0x80000000u) ? (u & 0x7FFFFFFFu) : ~u;
    return __uint_as_float(u);
}

// Agent-scope 16B load as 2 native u64 atomic loads (LLC-coherent read).
__device__ __forceinline__ float4 ag_load4(const float* ptr) {
    const unsigned long long* q = (const unsigned long long*)ptr;
    unsigned long long lo = AG_LOAD(q);
    unsigned long long hi = AG_LOAD(q + 1);
    float4 w;
    w.x = __uint_as_float((unsigned)lo);
    w.y = __uint_as_float((unsigned)(lo >> 32));
    w.z = __uint_as_float((unsigned)hi);
    w.w = __uint_as_float((unsigned)(hi >> 32));
    return w;
}

struct Params {
    const int* ei; const int* batch; int E;
    const float* W0; const float* b0; const float* Ws; const float* bs;
    const float* ln_g; const float* ln_b;
    const float* fW0; const float* fb0; const float* fWs; const float* fbs;
    const float* fln_g; const float* fln_b;
    const float* opW; const float* opb;
    float* hA; float* hAT;   // h[b][x][a][c] + transposed hT[b][y][x][c]
    float* hB; float* hBT;
    unsigned* PdgU; unsigned* PoffU; unsigned* PmnU;  // [4][2][64] encoded
    int* bar;                // 4 phases x (8 grp + root + flag), 64B-spaced
    float* out;              // 64
};

// Two-level grid barrier. NO threadfence: all inter-block data moves via
// agent-scope ops (LLC write-through); __syncthreads' vmcnt(0) drain orders
// them before the count — the proven tail-block mechanism (R5/R8).
__device__ __forceinline__ void gridbar(int* bar, int ph, int blk) {
    __syncthreads();
    if (threadIdx.x == 0) {
        int* base = bar + ph * 160;
        int g = blk >> 6;                         // 8 groups of 64
        int r = atomicAdd(base + g * 16, 1);
        if (r == 63) {
            int r2 = atomicAdd(base + 128, 1);
            if (r2 == 7) AG_STORE(base + 144, 1);
        }
        while (AG_LOAD(base + 144) == 0) __builtin_amdgcn_s_sleep(8);
    }
    __syncthreads();
}

__device__ __forceinline__ void pool_atomic(Params& p, int layer, int b_blk, int e,
                                            float mn, float off, float dg) {
    int o = layer * 128 + b_blk * 64 + e;
    atomicMax(&p.PdgU[o],  fenc(dg));
    atomicMax(&p.PoffU[o], fenc(off));
    atomicMax(&p.PmnU[o],  fenc(-mn));
}

// Block tiling: 512 blocks x 256 threads; block owns a 2x * 2y row tile.
// LDS ~74.8 KB -> 2 blocks/CU; all 512 co-resident (required for gridbar).
__launch_bounds__(256, 2)
__global__ void kfused(Params p) {
    const int tid  = threadIdx.x;
    const int blk  = blockIdx.x;
    const int c    = tid & 63;
    const int d    = c & 15;
    const int rl   = tid >> 6;
    const int rx   = rl >> 1;
    const int ry   = rl & 1;
    const int b_blk = blk >> 8;
    const int x0    = ((blk >> 4) & 15) * 2;
    const int y0    = (blk & 15) * 2;
    const int a_l  = c & 31;
    const int h1   = c >> 5;

    __shared__ float xslab2[2 * 32];
    __shared__ float yslab2[32 * 2];
    __shared__ __align__(16) float cA[64], cC[64], cW[64], cB0[64], cG[64], cBl[64];
    __shared__ float hstat[3][4];
    __shared__ float Wf0[64];
    __shared__ __align__(16) float hx2_s[2][2176];
    __shared__ __align__(16) float yT2_s[2][2176];
    __shared__ __align__(16) float WB[8704];   // T65|ST0 (phase0) -> FT/ST (layers)
    __shared__ float A1_s[4 * 132];
    __shared__ float K0h_s[4][4];
    __shared__ __align__(16) float xrow[4][64];
    __shared__ __align__(16) float xu_s[4][64];
    __shared__ __align__(16) float g16[16], b16[16];
    __shared__ float vals[4];
    __shared__ float scores_s[64];
    float* sm_mn  = &hx2_s[0][0];      // epilogue overlays (slabs dead by then)
    float* sm_off = sm_mn + 512;
    float* sm_dg  = sm_mn + 1024;
    float* psum   = sm_mn + 1536;

    // ================= PHASE 0 (R8 k0, verbatim; AG h-writes) =================
    if (tid < 64)  xslab2[tid] = 0.0f;
    if (tid >= 64 && tid < 128) yslab2[tid - 64] = 0.0f;

    if (tid < 64) {
        float Wc = p.W0[c], bc = p.b0[c];
        float sW = Wc, sB = bc;
        #pragma unroll
        for (int m = 1; m < 16; m <<= 1) {
            sW += __shfl_xor(sW, m, 16);
            sB += __shfl_xor(sB, m, 16);
        }
        float Ac = Wc - sW * 0.0625f;
        float Bc = bc - sB * 0.0625f;
        float sAA = Ac * Ac, sAB = Ac * Bc, sBB = Bc * Bc;
        #pragma unroll
        for (int m = 1; m < 16; m <<= 1) {
            sAA += __shfl_xor(sAA, m, 16);
            sAB += __shfl_xor(sAB, m, 16);
            sBB += __shfl_xor(sBB, m, 16);
        }
        cA[c] = Ac; cC[c] = Bc; cW[c] = Wc; cB0[c] = bc;
        cG[c] = p.ln_g[d]; cBl[c] = p.ln_b[d];
        if (d == 0) {
            hstat[0][c >> 4] = sAA * 0.0625f;
            hstat[1][c >> 4] = sAB * 0.0625f;
            hstat[2][c >> 4] = sBB * 0.0625f;
        }
        Wf0[tid] = p.fW0[tid * 65];
    }
    #pragma unroll
    for (int s = 0; s < 4; ++s) {       // T65 at WB+0, stride 68
        int i = tid + s * 256;
        int cc = i >> 4, u = i & 15;
        const float* src = p.fW0 + cc * 65 + 1 + 4 * u;
        float4 w = make_float4(src[0], src[1], src[2], src[3]);
        *(float4*)(WB + cc * 68 + 4 * ((u + 2 * cc) & 15)) = w;
    }
    #pragma unroll
    for (int s = 0; s < 4; ++s) {       // ST0 at WB+4352, stride 68
        int i = tid + s * 256;
        float4 w = ((const float4*)p.Ws)[i];
        int cc = i >> 4, u = i & 15;
        *(float4*)(WB + 4352 + cc * 68 + 4 * ((u + 2 * cc) & 15)) = w;
    }
    __syncthreads();

    for (int e2 = tid; e2 < p.E; e2 += 256) {
        int e0 = p.ei[e2], e1 = p.ei[p.E + e2];
        int g  = p.batch[e0];
        if (g == b_blk) {
            int ls = e0 - g * 32, ld = e1 - g * 32;
            unsigned dx = (unsigned)(ls - x0);
            if (dx < 2u) atomicAdd(&xslab2[dx * 32 + ld], 1.0f);
            unsigned dy = (unsigned)(ld - y0);
            if (dy < 2u) atomicAdd(&yslab2[ls * 2 + dy], 1.0f);
        }
    }
    __syncthreads();
    if (tid < 2)  xslab2[tid * 32 + x0 + tid] = 2.0f;
    if (tid >= 2 && tid < 4) { int j = tid - 2; yslab2[(y0 + j) * 2 + j] = 2.0f; }
    __syncthreads();

    {
        const float vx = xslab2[rx * 32 + a_l];
        const float vy = yslab2[a_l * 2 + ry];
        float s0, s1, is0, is1, w0m, w1m;
        #pragma unroll
        for (int hb = 0; hb < 2; ++hb) {
            const int hh = h1 + 2 * hb;
            float rsx = rsqrtf(fmaf(fmaf(hstat[0][hh], vx, 2.0f * hstat[1][hh]), vx, hstat[2][hh]) + EPS);
            float rsy = rsqrtf(fmaf(fmaf(hstat[0][hh], vy, 2.0f * hstat[1][hh]), vy, hstat[2][hh]) + EPS);
            float qq = 0.f, sp = 0.f, sq = 0.f;
            #pragma unroll
            for (int t = 0; t < 4; ++t) {
                int dd = hh * 16 + 4 * t;
                float4 av = *(const float4*)(cA + dd);
                float4 bv = *(const float4*)(cC + dd);
                float4 wv = *(const float4*)(cW + dd);
                float4 b0v = *(const float4*)(cB0 + dd);
                float4 gv = *(const float4*)(cG + dd);
                float4 blv = *(const float4*)(cBl + dd);
                float qx, qy, pp;
                qx = fmaf(av.x, vx, bv.x) * rsx * gv.x + blv.x;
                qy = fmaf(av.x, vy, bv.x) * rsy * gv.x + blv.x;
                qq = fmaf(qx, qy, qq);
                pp = fmaf(wv.x, vx, b0v.x) * fmaf(wv.x, vy, b0v.x); sp += pp; sq += pp * pp;
                qx = fmaf(av.y, vx, bv.y) * rsx * gv.y + blv.y;
                qy = fmaf(av.y, vy, bv.y) * rsy * gv.y + blv.y;
                qq = fmaf(qx, qy, qq);
                pp = fmaf(wv.y, vx, b0v.y) * fmaf(wv.y, vy, b0v.y); sp += pp; sq += pp * pp;
                qx = fmaf(av.z, vx, bv.z) * rsx * gv.z + blv.z;
                qy = fmaf(av.z, vy, bv.z) * rsy * gv.z + blv.z;
                qq = fmaf(qx, qy, qq);
                pp = fmaf(wv.z, vx, b0v.z) * fmaf(wv.z, vy, b0v.z); sp += pp; sq += pp * pp;
                qx = fmaf(av.w, vx, bv.w) * rsx * gv.w + blv.w;
                qy = fmaf(av.w, vy, bv.w) * rsy * gv.w + blv.w;
                qq = fmaf(qx, qy, qq);
                pp = fmaf(wv.w, vx, b0v.w) * fmaf(wv.w, vy, b0v.w); sp += pp; sq += pp * pp;
            }
            float ss = qq * 0.25f;
            float mu = sp * 0.0625f, var = fmaxf(sq * 0.0625f - mu * mu, 0.f);
            float is = rsqrtf(var + EPS);
            if (hb == 0) { s0 = ss; is0 = is; w0m = mu * is; }
            else         { s1 = ss; is1 = is; w1m = mu * is; }
        }

        float m0 = s0, m1 = s1;
        #pragma unroll
        for (int m = 1; m < 32; m <<= 1) {
            m0 = fmaxf(m0, __shfl_xor(m0, m));
            m1 = fmaxf(m1, __shfl_xor(m1, m));
        }
        float e0 = __expf(s0 - m0), e1 = __expf(s1 - m1);
        float l0 = e0, l1 = e1, k0a = e0 * w0m, k1a = e1 * w1m;
        #pragma unroll
        for (int m = 1; m < 32; m <<= 1) {
            l0 += __shfl_xor(l0, m);  l1 += __shfl_xor(l1, m);
            k0a += __shfl_xor(k0a, m); k1a += __shfl_xor(k1a, m);
        }
        A1_s[rl * 132 + h1 * 33 + a_l]       = e0 * is0 / l0;
        A1_s[rl * 132 + (h1 + 2) * 33 + a_l] = e1 * is1 / l1;
        if (a_l == 0) {
            K0h_s[rl][h1]     = k0a / l0;
            K0h_s[rl][h1 + 2] = k1a / l1;
        }

        {
            const int hc = c >> 4;
            const float Wc = cW[c], bc = cB0[c];
            float acc = 0.f;
            #pragma unroll
            for (int a = 0; a < 32; ++a) {
                float vx2 = xslab2[rx * 32 + a];
                float vy2 = yslab2[a * 2 + ry];
                float pv = fmaf(Wc, vx2, bc) * fmaf(Wc, vy2, bc);
                acc = fmaf(A1_s[rl * 132 + hc * 33 + a], pv, acc);
            }
            xu_s[rl][c] = (acc - K0h_s[rl][hc]) * cG[c] + cBl[c];
        }

        const float adjv = xslab2[rx * 32 + y0 + ry];
        float acc2 = fmaf(Wf0[c], adjv, p.fb0[c]);
        #pragma unroll
        for (int u = 0; u < 16; ++u) {
            float4 w = *(const float4*)(WB + c * 68 + 4 * ((u + 2 * c) & 15));
            float4 xr = *(const float4*)(&xu_s[rl][4 * u]);
            acc2 = fmaf(w.x, xr.x, acc2); acc2 = fmaf(w.y, xr.y, acc2);
            acc2 = fmaf(w.z, xr.z, acc2); acc2 = fmaf(w.w, xr.w, acc2);
        }
        float t1 = acc2;
        #pragma unroll
        for (int m = 1; m < 64; m <<= 1) t1 += __shfl_xor(t1, m, 64);
        float mu = t1 * (1.0f / 64.0f);
        float dv2 = acc2 - mu;
        float t2 = dv2 * dv2;
        #pragma unroll
        for (int m = 1; m < 64; m <<= 1) t2 += __shfl_xor(t2, m, 64);
        float xnew = dv2 * rsqrtf(t2 * (1.0f / 64.0f) + EPS) * p.fln_g[c] + p.fln_b[c];
        xrow[rl][c] = xnew;
    }
    __syncthreads();

    if (tid < 64) {
        float mn = 1e30f, off = -1e30f, dg = -1e30f;
        #pragma unroll
        for (int r2 = 0; r2 < 4; ++r2) {
            float v = xrow[r2][tid];
            mn = fminf(mn, v);
            if (x0 + (r2 >> 1) == y0 + (r2 & 1)) dg = fmaxf(dg, v);
            else off = fmaxf(off, v);
        }
        pool_atomic(p, 0, b_blk, tid, mn, off, dg);
    }
    {
        float acc = p.bs[c];
        #pragma unroll
        for (int u = 0; u < 16; ++u) {
            float4 w = *(const float4*)(WB + 4352 + c * 68 + 4 * ((u + 2 * c) & 15));
            float4 xr = *(const float4*)(&xrow[rl][4 * u]);
            acc = fmaf(w.x, xr.x, acc); acc = fmaf(w.y, xr.y, acc);
            acc = fmaf(w.z, xr.z, acc); acc = fmaf(w.w, xr.w, acc);
        }
        int x = x0 + rx, y = y0 + ry;
        AG_STORE(&p.hA[(b_blk * 1024 + x * 32 + y) * 64 + c], acc);
        AG_STORE(&p.hAT[((b_blk * 32 + y) * 32 + x) * 64 + c], acc);
    }
    gridbar(p.bar, 0, blk);

    // ================= PHASES 1..3 (R8 klayer body; AG transport) =============
    #pragma unroll 1
    for (int layer = 1; layer <= 3; ++layer) {
        const float* hin  = (layer == 2) ? p.hB  : p.hA;
        const float* hinT = (layer == 2) ? p.hBT : p.hAT;
        float* hout  = (layer == 1) ? p.hB  : p.hA;
        float* houtT = (layer == 1) ? p.hBT : p.hAT;

        {
            const float* sx0 = hin + (b_blk * 1024 + x0 * 32) * 64;
            const float* sx1 = hin + (b_blk * 1024 + (x0 + 1) * 32) * 64;
            const float* sy0 = hinT + (b_blk * 32 + y0) * 2048;
            const float* sy1 = hinT + (b_blk * 32 + y0 + 1) * 2048;
            #pragma unroll
            for (int s = 0; s < 2; ++s) {
                int ii = tid + s * 256;
                int a = ii >> 4, u = ii & 15, pr = (u + 2 * a) & 15;
                *(float4*)(&hx2_s[0][a * 68 + 4 * pr]) = ag_load4(sx0 + ii * 4);
                *(float4*)(&hx2_s[1][a * 68 + 4 * pr]) = ag_load4(sx1 + ii * 4);
                *(float4*)(&yT2_s[0][a * 68 + 4 * pr]) = ag_load4(sy0 + ii * 4);
                *(float4*)(&yT2_s[1][a * 68 + 4 * pr]) = ag_load4(sy1 + ii * 4);
            }
        }
        if (tid < 16) {
            g16[tid] = p.ln_g[layer * 16 + tid];
            b16[tid] = p.ln_b[layer * 16 + tid];
        }
        {
            const float4* fw = (const float4*)(p.fWs + (layer - 1) * 8192);
            #pragma unroll
            for (int s = 0; s < 8; ++s) {
                int i = tid + s * 256;
                float4 w = fw[i];
                int cc = i >> 5, u = i & 31;
                *(float4*)(WB + cc * 132 + 4 * ((u + 2 * cc) & 31)) = w;
            }
        }
        __syncthreads();

        float s0, s1, is0, is1, w0m, w1m;
        #pragma unroll
        for (int hb = 0; hb < 2; ++hb) {
            const int hh = h1 + 2 * hb;
            float4 xh4[4], yh4[4];
            float sxp = 0.f, sxq = 0.f, syp = 0.f, syq = 0.f;
            #pragma unroll
            for (int t = 0; t < 4; ++t) {
                int ps = 4 * (((hh * 4 + t) + 2 * a_l) & 15);
                float4 v = *(const float4*)(&hx2_s[rx][a_l * 68 + ps]);
                float4 y = *(const float4*)(&yT2_s[ry][a_l * 68 + ps]);
                xh4[t] = v; yh4[t] = y;
                sxp += v.x + v.y + v.z + v.w;
                sxq += v.x*v.x + v.y*v.y + v.z*v.z + v.w*v.w;
                syp += y.x + y.y + y.z + y.w;
                syq += y.x*y.x + y.y*y.y + y.z*y.z + y.w*y.w;
            }
            float mxm = sxp * 0.0625f;
            float rsx = rsqrtf(fmaxf(sxq * 0.0625f - mxm * mxm, 0.f) + EPS);
            float mym = syp * 0.0625f;
            float rsy = rsqrtf(fmaxf(syq * 0.0625f - mym * mym, 0.f) + EPS);
            float qq = 0.f, sp = 0.f, sq = 0.f;
            #pragma unroll
            for (int t = 0; t < 4; ++t) {
                float4 g4 = *(const float4*)(g16 + 4 * t);
                float4 b4 = *(const float4*)(b16 + 4 * t);
                float4 xh = xh4[t], yh = yh4[t];
                float qx, qy, pp;
                qx = (xh.x - mxm) * rsx * g4.x + b4.x;
                qy = (yh.x - mym) * rsy * g4.x + b4.x;
                qq = fmaf(qx, qy, qq);  pp = xh.x * yh.x; sp += pp; sq += pp * pp;
                qx = (xh.y - mxm) * rsx * g4.y + b4.y;
                qy = (yh.y - mym) * rsy * g4.y + b4.y;
                qq = fmaf(qx, qy, qq);  pp = xh.y * yh.y; sp += pp; sq += pp * pp;
                qx = (xh.z - mxm) * rsx * g4.z + b4.z;
                qy = (yh.z - mym) * rsy * g4.z + b4.z;
                qq = fmaf(qx, qy, qq);  pp = xh.z * yh.z; sp += pp; sq += pp * pp;
                qx = (xh.w - mxm) * rsx * g4.w + b4.w;
                qy = (yh.w - mym) * rsy * g4.w + b4.w;
                qq = fmaf(qx, qy, qq);  pp = xh.w * yh.w; sp += pp; sq += pp * pp;
            }
            float ss = qq * 0.25f;
            float mu = sp * 0.0625f, var = fmaxf(sq * 0.0625f - mu * mu, 0.f);
            float is = rsqrtf(var + EPS);
            if (hb == 0) { s0 = ss; is0 = is; w0m = mu * is; }
            else         { s1 = ss; is1 = is; w1m = mu * is; }
        }

        float m0 = s0, m1 = s1;
        #pragma unroll
        for (int m = 1; m < 32; m <<= 1) {
            m0 = fmaxf(m0, __shfl_xor(m0, m));
            m1 = fmaxf(m1, __shfl_xor(m1, m));
        }
        float e0 = __expf(s0 - m0), e1 = __expf(s1 - m1);
        float l0 = e0, l1 = e1, k0a = e0 * w0m, k1a = e1 * w1m;
        #pragma unroll
        for (int m = 1; m < 32; m <<= 1) {
            l0 += __shfl_xor(l0, m);  l1 += __shfl_xor(l1, m);
            k0a += __shfl_xor(k0a, m); k1a += __shfl_xor(k1a, m);
        }
        A1_s[rl * 132 + h1 * 33 + a_l]       = e0 * is0 / l0;
        A1_s[rl * 132 + (h1 + 2) * 33 + a_l] = e1 * is1 / l1;
        if (a_l == 0) {
            K0h_s[rl][h1]     = k0a / l0;
            K0h_s[rl][h1 + 2] = k1a / l1;
        }

        {
            const int hc = c >> 4;
            const int ce = c & 3;
            float acc = 0.f;
            #pragma unroll
            for (int a = 0; a < 32; ++a) {
                int ps = 4 * (((c >> 2) + 2 * a) & 15) + ce;
                float hxv = hx2_s[rx][a * 68 + ps];
                float hyv = yT2_s[ry][a * 68 + ps];
                acc = fmaf(A1_s[rl * 132 + hc * 33 + a], hxv * hyv, acc);
            }
            xu_s[rl][c] = (acc - K0h_s[rl][hc]) * g16[d] + b16[d];
        }

        float acc2 = p.fbs[(layer - 1) * 64 + c];
        #pragma unroll
        for (int u = 0; u < 16; ++u) {
            float4 w = *(const float4*)(WB + c * 132 + 4 * ((u + 2 * c) & 31));
            float4 xr = *(const float4*)(&xrow[rl][4 * u]);
            acc2 = fmaf(w.x, xr.x, acc2); acc2 = fmaf(w.y, xr.y, acc2);
            acc2 = fmaf(w.z, xr.z, acc2); acc2 = fmaf(w.w, xr.w, acc2);
        }
        #pragma unroll
        for (int u = 16; u < 32; ++u) {
            float4 w = *(const float4*)(WB + c * 132 + 4 * ((u + 2 * c) & 31));
            float4 xr = *(const float4*)(&xu_s[rl][4 * (u - 16)]);
            acc2 = fmaf(w.x, xr.x, acc2); acc2 = fmaf(w.y, xr.y, acc2);
            acc2 = fmaf(w.z, xr.z, acc2); acc2 = fmaf(w.w, xr.w, acc2);
        }
        float t1 = acc2;
        #pragma unroll
        for (int m = 1; m < 64; m <<= 1) t1 += __shfl_xor(t1, m, 64);
        float mu = t1 * (1.0f / 64.0f);
        float dv2 = acc2 - mu;
        float t2 = dv2 * dv2;
        #pragma unroll
        for (int m = 1; m < 64; m <<= 1) t2 += __shfl_xor(t2, m, 64);
        float xnew = dv2 * rsqrtf(t2 * (1.0f / 64.0f) + EPS) *
                     p.fln_g[layer * 64 + c] + p.fln_b[layer * 64 + c];
        __syncthreads();          // WB/xrow reads complete
        xrow[rl][c] = xnew;
        if (layer < 3) {
            // restage ST = Ws[layer] into WB (stride 68; FT dead after fin)
            const float4* sw = (const float4*)(p.Ws + layer * 4096);
            #pragma unroll
            for (int s = 0; s < 4; ++s) {
                int i = tid + s * 256;
                float4 w = sw[i];
                int cc = i >> 4, u = i & 15;
                *(float4*)(WB + cc * 68 + 4 * ((u + 2 * cc) & 15)) = w;
            }
        }
        __syncthreads();

        if (tid < 64) {
            float mn = 1e30f, off = -1e30f, dg = -1e30f;
            #pragma unroll
            for (int r2 = 0; r2 < 4; ++r2) {
                float v = xrow[r2][tid];
                mn = fminf(mn, v);
                if (x0 + (r2 >> 1) == y0 + (r2 & 1)) dg = fmaxf(dg, v);
                else off = fmaxf(off, v);
            }
            pool_atomic(p, layer, b_blk, tid, mn, off, dg);
        }

        if (layer < 3) {
            float acc = p.bs[layer * 64 + c];
            #pragma unroll
            for (int u = 0; u < 16; ++u) {
                float4 w = *(const float4*)(WB + c * 68 + 4 * ((u + 2 * c) & 15));
                float4 xr = *(const float4*)(&xrow[rl][4 * u]);
                acc = fmaf(w.x, xr.x, acc); acc = fmaf(w.y, xr.y, acc);
                acc = fmaf(w.z, xr.z, acc); acc = fmaf(w.w, xr.w, acc);
            }
            int x = x0 + rx, y = y0 + ry;
            AG_STORE(&hout[(b_blk * 1024 + x * 32 + y) * 64 + c], acc);
            AG_STORE(&houtT[((b_blk * 32 + y) * 32 + x) * 64 + c], acc);
        }
        gridbar(p.bar, layer, blk);
    }

    // ================= EPILOGUE (block 0 only) =================
    if (blk != 0) return;

    #pragma unroll
    for (int s = 0; s < 2; ++s) {
        int slot = tid + s * 256;
        unsigned ud = AG_LOAD(&p.PdgU[slot]);
        unsigned uo = AG_LOAD(&p.PoffU[slot]);
        unsigned um = AG_LOAD(&p.PmnU[slot]);
        sm_dg[slot]  = fdec(ud);
        sm_off[slot] = fdec(uo);
        sm_mn[slot]  = -fdec(um);
    }
    __syncthreads();
    if (tid < 4) {
        float gmx = -1e30f, gmn = 1e30f;
        for (int i2 = 0; i2 < 128; ++i2) {
            gmx = fmaxf(gmx, sm_dg[tid * 128 + i2]);
            gmn = fminf(gmn, sm_mn[tid * 128 + i2]);
        }
        vals[tid] = fabsf(gmx - gmn);
    }
    __syncthreads();
    {
        int bb = tid >> 7, cc = (tid >> 2) & 31, pp = tid & 3;
        float a2 = 0.0f;
        for (int l = 0; l < 4; ++l) {
            float val = vals[l];
            const float* Wr = p.opW + l * 4096 + cc * 128;
            int base = l * 128 + bb * 64;
            for (int j = pp * 32; j < pp * 32 + 32; ++j) {
                float pv;
                if (j < 64) pv = sm_dg[base + j];
                else        pv = fmaxf(sm_off[base + j - 64], sm_dg[base + j - 64] - val);
                a2 = fmaf(Wr[j], pv, a2);
            }
        }
        psum[tid] = a2;
    }
    __syncthreads();
    if (tid < 64) {
        int bb = tid >> 5, cc = tid & 31;
        float a2 = 0.0f;
        for (int l = 0; l < 4; ++l) a2 += p.opb[l * 32 + cc];
        for (int pp = 0; pp < 4; ++pp) a2 += psum[bb * 128 + cc * 4 + pp];
        scores_s[tid] = a2;
    }
    __syncthreads();
    if (tid < 32) {
        float sA = scores_s[tid], sB = scores_s[32 + tid];
        float mu2 = 0.5f * (sA + sB);
        float va = 0.5f * ((sA - mu2) * (sA - mu2) + (sB - mu2) * (sB - mu2));
        float inv = rsqrtf(va + EPS);
        p.out[tid]      = (sA - mu2) * inv;
        p.out[32 + tid] = (sB - mu2) * inv;
    }
}

// ---------------------------------------------------------------------------
extern "C" void kernel_launch(void* const* d_in, const int* in_sizes, int n_in,
                              void* d_out, int out_size, void* d_ws, size_t ws_size,
                              hipStream_t stream) {
    Params prm;
    prm.ei    = (const int*)d_in[0];
    prm.batch = (const int*)d_in[1];
    prm.E     = in_sizes[0] / 2;
    prm.W0    = (const float*)d_in[2];
    prm.b0    = (const float*)d_in[3];
    prm.Ws    = (const float*)d_in[4];
    prm.bs    = (const float*)d_in[5];
    prm.ln_g  = (const float*)d_in[6];
    prm.ln_b  = (const float*)d_in[7];
    prm.fW0   = (const float*)d_in[8];
    prm.fb0   = (const float*)d_in[9];
    prm.fWs   = (const float*)d_in[10];
    prm.fbs   = (const float*)d_in[11];
    prm.fln_g = (const float*)d_in[12];
    prm.fln_b = (const float*)d_in[13];
    prm.opW   = (const float*)d_in[14];
    prm.opb   = (const float*)d_in[15];

    float* ws = (float*)d_ws;
    prm.hA    = ws;                     // 131072 each
    prm.hAT   = prm.hA  + 131072;
    prm.hB    = prm.hAT + 131072;
    prm.hBT   = prm.hB  + 131072;
    unsigned* pu = (unsigned*)(prm.hBT + 131072);
    prm.PdgU  = pu;                     // [4][2][64] = 512 each
    prm.PoffU = pu + 512;
    prm.PmnU  = pu + 1024;
    prm.bar   = (int*)(pu + 1536);      // 4 phases x 160 ints (64B-spaced)
    prm.out   = (float*)d_out;
    // ws total: 4*131072 floats + (1536+640) u32 = 2.11 MB

    hipMemsetAsync(pu, 0, (1536 + 640) * sizeof(unsigned), stream);
    kfused<<<512, 256, 0, stream>>>(prm);
}

// Round 11
// 165.380 us; speedup vs baseline: 3.3856x; 1.0255x over previous
//
#include <hip/hip_runtime.h>
#include <math.h>

// Shapes fixed by the reference: B=2, N=32, L=4, ED=64, H=4, HD=16
#define EPS 1e-5f

#define AG_LOAD(p)     __hip_atomic_load((p), __ATOMIC_RELAXED, __HIP_MEMORY_SCOPE_AGENT)
#define AG_STORE(p, v) __hip_atomic_store((p), (v), __ATOMIC_RELAXED, __HIP_MEMORY_SCOPE_AGENT)

// Order-preserving float<->uint encoding for atomicMax-based float max.
__device__ __forceinline__ unsigned fenc(float f) {
    unsigned u = __float_as_uint(f);
    return (u & 0x80000000u) ? ~u : (u | 0x80000000u);
}
__device__ __forceinline__ float fdec(unsigned u) {
    u = (u & 0x80000000u) ? (u & 0x7FFFFFFFu) : ~u;
    return __uint_as_float(u);
}

struct Params {
    const int* ei; const int* batch; int E;
    const float* W0; const float* b0; const float* Ws; const float* bs;
    const float* ln_g; const float* ln_b;
    const float* fW0; const float* fb0; const float* fWs; const float* fbs;
    const float* fln_g; const float* fln_b;
    const float* opW; const float* opb;
    // Distinct buffer per layer-edge (NO reuse: a reused buffer could leave
    // stale CLEAN copies in consumer L2s from the earlier phase's reads).
    float* hA; float* hAT;   // L0 -> L1
    float* hB; float* hBT;   // L1 -> L2
    float* hC; float* hCT;   // L2 -> L3
    unsigned* PdgU; unsigned* PoffU; unsigned* PmnU;  // [4][2][64] encoded
    int* bar;                // 3 phases x 160 ints + tail counter
    float* out;              // 64
};

// Coherence model (validated by the working R8 chain): dispatch boundaries do
// L2 WB+INV, so this kernel starts with invalidated per-XCD L2s. Producers
// write h ONLY via agent-scope stores (bypass L2 -> LLC). Each h buffer is
// written in one phase and first touched by consumers after the barrier, so
// no L2 can hold a stale copy -> consumers use plain coalesced float4 loads.
// __syncthreads' vmcnt(0) drain before the barrier count publishes the AG
// stores to LLC (the proven R5/R8 tail-block mechanism; no threadfence).
__device__ __forceinline__ void gridbar(int* bar, int ph, int blk) {
    __syncthreads();
    if (threadIdx.x == 0) {
        int* base = bar + ph * 160;
        int g = blk >> 6;                         // 8 groups of 64
        int r = atomicAdd(base + g * 16, 1);
        if (r == 63) {
            int r2 = atomicAdd(base + 128, 1);
            if (r2 == 7) AG_STORE(base + 144, 1);
        }
        while (AG_LOAD(base + 144) == 0) __builtin_amdgcn_s_sleep(8);
    }
    __syncthreads();
}

__device__ __forceinline__ void pool_atomic(Params& p, int layer, int b_blk, int e,
                                            float mn, float off, float dg) {
    int o = layer * 128 + b_blk * 64 + e;
    atomicMax(&p.PdgU[o],  fenc(dg));
    atomicMax(&p.PoffU[o], fenc(off));
    atomicMax(&p.PmnU[o],  fenc(-mn));
}

// Block tiling: 512 blocks x 256 threads; block owns a 2x * 2y row tile.
// LDS ~75 KB -> 2 blocks/CU; all 512 co-resident (required for gridbar).
__launch_bounds__(256, 2)
__global__ void kfused(Params p) {
    const int tid  = threadIdx.x;
    const int blk  = blockIdx.x;
    const int c    = tid & 63;
    const int d    = c & 15;
    const int rl   = tid >> 6;
    const int rx   = rl >> 1;
    const int ry   = rl & 1;
    const int b_blk = blk >> 8;
    const int x0    = ((blk >> 4) & 15) * 2;
    const int y0    = (blk & 15) * 2;
    const int a_l  = c & 31;
    const int h1   = c >> 5;

    __shared__ float xslab2[2 * 32];
    __shared__ float yslab2[32 * 2];
    __shared__ __align__(16) float cA[64], cC[64], cW[64], cB0[64], cG[64], cBl[64];
    __shared__ float hstat[3][4];
    __shared__ float Wf0[64];
    __shared__ __align__(16) float hx2_s[2][2176];
    __shared__ __align__(16) float yT2_s[2][2176];
    __shared__ __align__(16) float WB[8704];   // T65|ST0 (phase0) -> FT/ST (layers)
    __shared__ float A1_s[4 * 132];
    __shared__ float K0h_s[4][4];
    __shared__ __align__(16) float xrow[4][64];
    __shared__ __align__(16) float xu_s[4][64];
    __shared__ __align__(16) float g16[16], b16[16];
    __shared__ float vals[4];
    __shared__ float scores_s[64];
    __shared__ int tailflag;
    float* sm_mn  = &hx2_s[0][0];      // epilogue overlays (slabs dead by then)
    float* sm_off = sm_mn + 512;
    float* sm_dg  = sm_mn + 1024;
    float* psum   = sm_mn + 1536;

    // ================= PHASE 0 (R8 k0, verbatim; AG h-writes) =================
    if (tid < 64)  xslab2[tid] = 0.0f;
    if (tid >= 64 && tid < 128) yslab2[tid - 64] = 0.0f;

    if (tid < 64) {
        float Wc = p.W0[c], bc = p.b0[c];
        float sW = Wc, sB = bc;
        #pragma unroll
        for (int m = 1; m < 16; m <<= 1) {
            sW += __shfl_xor(sW, m, 16);
            sB += __shfl_xor(sB, m, 16);
        }
        float Ac = Wc - sW * 0.0625f;
        float Bc = bc - sB * 0.0625f;
        float sAA = Ac * Ac, sAB = Ac * Bc, sBB = Bc * Bc;
        #pragma unroll
        for (int m = 1; m < 16; m <<= 1) {
            sAA += __shfl_xor(sAA, m, 16);
            sAB += __shfl_xor(sAB, m, 16);
            sBB += __shfl_xor(sBB, m, 16);
        }
        cA[c] = Ac; cC[c] = Bc; cW[c] = Wc; cB0[c] = bc;
        cG[c] = p.ln_g[d]; cBl[c] = p.ln_b[d];
        if (d == 0) {
            hstat[0][c >> 4] = sAA * 0.0625f;
            hstat[1][c >> 4] = sAB * 0.0625f;
            hstat[2][c >> 4] = sBB * 0.0625f;
        }
        Wf0[tid] = p.fW0[tid * 65];
    }
    #pragma unroll
    for (int s = 0; s < 4; ++s) {       // T65 at WB+0, stride 68
        int i = tid + s * 256;
        int cc = i >> 4, u = i & 15;
        const float* src = p.fW0 + cc * 65 + 1 + 4 * u;
        float4 w = make_float4(src[0], src[1], src[2], src[3]);
        *(float4*)(WB + cc * 68 + 4 * ((u + 2 * cc) & 15)) = w;
    }
    #pragma unroll
    for (int s = 0; s < 4; ++s) {       // ST0 at WB+4352, stride 68
        int i = tid + s * 256;
        float4 w = ((const float4*)p.Ws)[i];
        int cc = i >> 4, u = i & 15;
        *(float4*)(WB + 4352 + cc * 68 + 4 * ((u + 2 * cc) & 15)) = w;
    }
    __syncthreads();

    for (int e2 = tid; e2 < p.E; e2 += 256) {
        int e0 = p.ei[e2], e1 = p.ei[p.E + e2];
        int g  = p.batch[e0];
        if (g == b_blk) {
            int ls = e0 - g * 32, ld = e1 - g * 32;
            unsigned dx = (unsigned)(ls - x0);
            if (dx < 2u) atomicAdd(&xslab2[dx * 32 + ld], 1.0f);
            unsigned dy = (unsigned)(ld - y0);
            if (dy < 2u) atomicAdd(&yslab2[ls * 2 + dy], 1.0f);
        }
    }
    __syncthreads();
    if (tid < 2)  xslab2[tid * 32 + x0 + tid] = 2.0f;
    if (tid >= 2 && tid < 4) { int j = tid - 2; yslab2[(y0 + j) * 2 + j] = 2.0f; }
    __syncthreads();

    {
        const float vx = xslab2[rx * 32 + a_l];
        const float vy = yslab2[a_l * 2 + ry];
        float s0, s1, is0, is1, w0m, w1m;
        #pragma unroll
        for (int hb = 0; hb < 2; ++hb) {
            const int hh = h1 + 2 * hb;
            float rsx = rsqrtf(fmaf(fmaf(hstat[0][hh], vx, 2.0f * hstat[1][hh]), vx, hstat[2][hh]) + EPS);
            float rsy = rsqrtf(fmaf(fmaf(hstat[0][hh], vy, 2.0f * hstat[1][hh]), vy, hstat[2][hh]) + EPS);
            float qq = 0.f, sp = 0.f, sq = 0.f;
            #pragma unroll
            for (int t = 0; t < 4; ++t) {
                int dd = hh * 16 + 4 * t;
                float4 av = *(const float4*)(cA + dd);
                float4 bv = *(const float4*)(cC + dd);
                float4 wv = *(const float4*)(cW + dd);
                float4 b0v = *(const float4*)(cB0 + dd);
                float4 gv = *(const float4*)(cG + dd);
                float4 blv = *(const float4*)(cBl + dd);
                float qx, qy, pp;
                qx = fmaf(av.x, vx, bv.x) * rsx * gv.x + blv.x;
                qy = fmaf(av.x, vy, bv.x) * rsy * gv.x + blv.x;
                qq = fmaf(qx, qy, qq);
                pp = fmaf(wv.x, vx, b0v.x) * fmaf(wv.x, vy, b0v.x); sp += pp; sq += pp * pp;
                qx = fmaf(av.y, vx, bv.y) * rsx * gv.y + blv.y;
                qy = fmaf(av.y, vy, bv.y) * rsy * gv.y + blv.y;
                qq = fmaf(qx, qy, qq);
                pp = fmaf(wv.y, vx, b0v.y) * fmaf(wv.y, vy, b0v.y); sp += pp; sq += pp * pp;
                qx = fmaf(av.z, vx, bv.z) * rsx * gv.z + blv.z;
                qy = fmaf(av.z, vy, bv.z) * rsy * gv.z + blv.z;
                qq = fmaf(qx, qy, qq);
                pp = fmaf(wv.z, vx, b0v.z) * fmaf(wv.z, vy, b0v.z); sp += pp; sq += pp * pp;
                qx = fmaf(av.w, vx, bv.w) * rsx * gv.w + blv.w;
                qy = fmaf(av.w, vy, bv.w) * rsy * gv.w + blv.w;
                qq = fmaf(qx, qy, qq);
                pp = fmaf(wv.w, vx, b0v.w) * fmaf(wv.w, vy, b0v.w); sp += pp; sq += pp * pp;
            }
            float ss = qq * 0.25f;
            float mu = sp * 0.0625f, var = fmaxf(sq * 0.0625f - mu * mu, 0.f);
            float is = rsqrtf(var + EPS);
            if (hb == 0) { s0 = ss; is0 = is; w0m = mu * is; }
            else         { s1 = ss; is1 = is; w1m = mu * is; }
        }

        float m0 = s0, m1 = s1;
        #pragma unroll
        for (int m = 1; m < 32; m <<= 1) {
            m0 = fmaxf(m0, __shfl_xor(m0, m));
            m1 = fmaxf(m1, __shfl_xor(m1, m));
        }
        float e0 = __expf(s0 - m0), e1 = __expf(s1 - m1);
        float l0 = e0, l1 = e1, k0a = e0 * w0m, k1a = e1 * w1m;
        #pragma unroll
        for (int m = 1; m < 32; m <<= 1) {
            l0 += __shfl_xor(l0, m);  l1 += __shfl_xor(l1, m);
            k0a += __shfl_xor(k0a, m); k1a += __shfl_xor(k1a, m);
        }
        A1_s[rl * 132 + h1 * 33 + a_l]       = e0 * is0 / l0;
        A1_s[rl * 132 + (h1 + 2) * 33 + a_l] = e1 * is1 / l1;
        if (a_l == 0) {
            K0h_s[rl][h1]     = k0a / l0;
            K0h_s[rl][h1 + 2] = k1a / l1;
        }

        {
            const int hc = c >> 4;
            const float Wc = cW[c], bc = cB0[c];
            float acc = 0.f;
            #pragma unroll
            for (int a = 0; a < 32; ++a) {
                float vx2 = xslab2[rx * 32 + a];
                float vy2 = yslab2[a * 2 + ry];
                float pv = fmaf(Wc, vx2, bc) * fmaf(Wc, vy2, bc);
                acc = fmaf(A1_s[rl * 132 + hc * 33 + a], pv, acc);
            }
            xu_s[rl][c] = (acc - K0h_s[rl][hc]) * cG[c] + cBl[c];
        }

        const float adjv = xslab2[rx * 32 + y0 + ry];
        float acc2 = fmaf(Wf0[c], adjv, p.fb0[c]);
        #pragma unroll
        for (int u = 0; u < 16; ++u) {
            float4 w = *(const float4*)(WB + c * 68 + 4 * ((u + 2 * c) & 15));
            float4 xr = *(const float4*)(&xu_s[rl][4 * u]);
            acc2 = fmaf(w.x, xr.x, acc2); acc2 = fmaf(w.y, xr.y, acc2);
            acc2 = fmaf(w.z, xr.z, acc2); acc2 = fmaf(w.w, xr.w, acc2);
        }
        float t1 = acc2;
        #pragma unroll
        for (int m = 1; m < 64; m <<= 1) t1 += __shfl_xor(t1, m, 64);
        float mu = t1 * (1.0f / 64.0f);
        float dv2 = acc2 - mu;
        float t2 = dv2 * dv2;
        #pragma unroll
        for (int m = 1; m < 64; m <<= 1) t2 += __shfl_xor(t2, m, 64);
        float xnew = dv2 * rsqrtf(t2 * (1.0f / 64.0f) + EPS) * p.fln_g[c] + p.fln_b[c];
        xrow[rl][c] = xnew;
    }
    __syncthreads();

    if (tid < 64) {
        float mn = 1e30f, off = -1e30f, dg = -1e30f;
        #pragma unroll
        for (int r2 = 0; r2 < 4; ++r2) {
            float v = xrow[r2][tid];
            mn = fminf(mn, v);
            if (x0 + (r2 >> 1) == y0 + (r2 & 1)) dg = fmaxf(dg, v);
            else off = fmaxf(off, v);
        }
        pool_atomic(p, 0, b_blk, tid, mn, off, dg);
    }
    {
        float acc = p.bs[c];
        #pragma unroll
        for (int u = 0; u < 16; ++u) {
            float4 w = *(const float4*)(WB + 4352 + c * 68 + 4 * ((u + 2 * c) & 15));
            float4 xr = *(const float4*)(&xrow[rl][4 * u]);
            acc = fmaf(w.x, xr.x, acc); acc = fmaf(w.y, xr.y, acc);
            acc = fmaf(w.z, xr.z, acc); acc = fmaf(w.w, xr.w, acc);
        }
        int x = x0 + rx, y = y0 + ry;
        AG_STORE(&p.hA[(b_blk * 1024 + x * 32 + y) * 64 + c], acc);
        AG_STORE(&p.hAT[((b_blk * 32 + y) * 32 + x) * 64 + c], acc);
    }
    gridbar(p.bar, 0, blk);

    // ================= PHASES 1..3 (normal wide loads; AG stores) =============
    #pragma unroll 1
    for (int layer = 1; layer <= 3; ++layer) {
        const float* hin  = (layer == 1) ? p.hA  : (layer == 2) ? p.hB  : p.hC;
        const float* hinT = (layer == 1) ? p.hAT : (layer == 2) ? p.hBT : p.hCT;
        float* hout  = (layer == 1) ? p.hB  : p.hC;
        float* houtT = (layer == 1) ? p.hBT : p.hCT;

        {
            const float4* sx0 = (const float4*)(hin + (b_blk * 1024 + x0 * 32) * 64);
            const float4* sx1 = (const float4*)(hin + (b_blk * 1024 + (x0 + 1) * 32) * 64);
            const float4* sy0 = (const float4*)(hinT + (b_blk * 32 + y0) * 2048);
            const float4* sy1 = (const float4*)(hinT + (b_blk * 32 + y0 + 1) * 2048);
            #pragma unroll
            for (int s = 0; s < 2; ++s) {
                int ii = tid + s * 256;
                int a = ii >> 4, u = ii & 15, pr = (u + 2 * a) & 15;
                *(float4*)(&hx2_s[0][a * 68 + 4 * pr]) = sx0[ii];
                *(float4*)(&hx2_s[1][a * 68 + 4 * pr]) = sx1[ii];
                *(float4*)(&yT2_s[0][a * 68 + 4 * pr]) = sy0[ii];
                *(float4*)(&yT2_s[1][a * 68 + 4 * pr]) = sy1[ii];
            }
        }
        if (tid < 16) {
            g16[tid] = p.ln_g[layer * 16 + tid];
            b16[tid] = p.ln_b[layer * 16 + tid];
        }
        {
            const float4* fw = (const float4*)(p.fWs + (layer - 1) * 8192);
            #pragma unroll
            for (int s = 0; s < 8; ++s) {
                int i = tid + s * 256;
                float4 w = fw[i];
                int cc = i >> 5, u = i & 31;
                *(float4*)(WB + cc * 132 + 4 * ((u + 2 * cc) & 31)) = w;
            }
        }
        __syncthreads();

        float s0, s1, is0, is1, w0m, w1m;
        #pragma unroll
        for (int hb = 0; hb < 2; ++hb) {
            const int hh = h1 + 2 * hb;
            float4 xh4[4], yh4[4];
            float sxp = 0.f, sxq = 0.f, syp = 0.f, syq = 0.f;
            #pragma unroll
            for (int t = 0; t < 4; ++t) {
                int ps = 4 * (((hh * 4 + t) + 2 * a_l) & 15);
                float4 v = *(const float4*)(&hx2_s[rx][a_l * 68 + ps]);
                float4 y = *(const float4*)(&yT2_s[ry][a_l * 68 + ps]);
                xh4[t] = v; yh4[t] = y;
                sxp += v.x + v.y + v.z + v.w;
                sxq += v.x*v.x + v.y*v.y + v.z*v.z + v.w*v.w;
                syp += y.x + y.y + y.z + y.w;
                syq += y.x*y.x + y.y*y.y + y.z*y.z + y.w*y.w;
            }
            float mxm = sxp * 0.0625f;
            float rsx = rsqrtf(fmaxf(sxq * 0.0625f - mxm * mxm, 0.f) + EPS);
            float mym = syp * 0.0625f;
            float rsy = rsqrtf(fmaxf(syq * 0.0625f - mym * mym, 0.f) + EPS);
            float qq = 0.f, sp = 0.f, sq = 0.f;
            #pragma unroll
            for (int t = 0; t < 4; ++t) {
                float4 g4 = *(const float4*)(g16 + 4 * t);
                float4 b4 = *(const float4*)(b16 + 4 * t);
                float4 xh = xh4[t], yh = yh4[t];
                float qx, qy, pp;
                qx = (xh.x - mxm) * rsx * g4.x + b4.x;
                qy = (yh.x - mym) * rsy * g4.x + b4.x;
                qq = fmaf(qx, qy, qq);  pp = xh.x * yh.x; sp += pp; sq += pp * pp;
                qx = (xh.y - mxm) * rsx * g4.y + b4.y;
                qy = (yh.y - mym) * rsy * g4.y + b4.y;
                qq = fmaf(qx, qy, qq);  pp = xh.y * yh.y; sp += pp; sq += pp * pp;
                qx = (xh.z - mxm) * rsx * g4.z + b4.z;
                qy = (yh.z - mym) * rsy * g4.z + b4.z;
                qq = fmaf(qx, qy, qq);  pp = xh.z * yh.z; sp += pp; sq += pp * pp;
                qx = (xh.w - mxm) * rsx * g4.w + b4.w;
                qy = (yh.w - mym) * rsy * g4.w + b4.w;
                qq = fmaf(qx, qy, qq);  pp = xh.w * yh.w; sp += pp; sq += pp * pp;
            }
            float ss = qq * 0.25f;
            float mu = sp * 0.0625f, var = fmaxf(sq * 0.0625f - mu * mu, 0.f);
            float is = rsqrtf(var + EPS);
            if (hb == 0) { s0 = ss; is0 = is; w0m = mu * is; }
            else         { s1 = ss; is1 = is; w1m = mu * is; }
        }

        float m0 = s0, m1 = s1;
        #pragma unroll
        for (int m = 1; m < 32; m <<= 1) {
            m0 = fmaxf(m0, __shfl_xor(m0, m));
            m1 = fmaxf(m1, __shfl_xor(m1, m));
        }
        float e0 = __expf(s0 - m0), e1 = __expf(s1 - m1);
        float l0 = e0, l1 = e1, k0a = e0 * w0m, k1a = e1 * w1m;
        #pragma unroll
        for (int m = 1; m < 32; m <<= 1) {
            l0 += __shfl_xor(l0, m);  l1 += __shfl_xor(l1, m);
            k0a += __shfl_xor(k0a, m); k1a += __shfl_xor(k1a, m);
        }
        A1_s[rl * 132 + h1 * 33 + a_l]       = e0 * is0 / l0;
        A1_s[rl * 132 + (h1 + 2) * 33 + a_l] = e1 * is1 / l1;
        if (a_l == 0) {
            K0h_s[rl][h1]     = k0a / l0;
            K0h_s[rl][h1 + 2] = k1a / l1;
        }

        {
            const int hc = c >> 4;
            const int ce = c & 3;
            float acc = 0.f;
            #pragma unroll
            for (int a = 0; a < 32; ++a) {
                int ps = 4 * (((c >> 2) + 2 * a) & 15) + ce;
                float hxv = hx2_s[rx][a * 68 + ps];
                float hyv = yT2_s[ry][a * 68 + ps];
                acc = fmaf(A1_s[rl * 132 + hc * 33 + a], hxv * hyv, acc);
            }
            xu_s[rl][c] = (acc - K0h_s[rl][hc]) * g16[d] + b16[d];
        }

        float acc2 = p.fbs[(layer - 1) * 64 + c];
        #pragma unroll
        for (int u = 0; u < 16; ++u) {
            float4 w = *(const float4*)(WB + c * 132 + 4 * ((u + 2 * c) & 31));
            float4 xr = *(const float4*)(&xrow[rl][4 * u]);
            acc2 = fmaf(w.x, xr.x, acc2); acc2 = fmaf(w.y, xr.y, acc2);
            acc2 = fmaf(w.z, xr.z, acc2); acc2 = fmaf(w.w, xr.w, acc2);
        }
        #pragma unroll
        for (int u = 16; u < 32; ++u) {
            float4 w = *(const float4*)(WB + c * 132 + 4 * ((u + 2 * c) & 31));
            float4 xr = *(const float4*)(&xu_s[rl][4 * (u - 16)]);
            acc2 = fmaf(w.x, xr.x, acc2); acc2 = fmaf(w.y, xr.y, acc2);
            acc2 = fmaf(w.z, xr.z, acc2); acc2 = fmaf(w.w, xr.w, acc2);
        }
        float t1 = acc2;
        #pragma unroll
        for (int m = 1; m < 64; m <<= 1) t1 += __shfl_xor(t1, m, 64);
        float mu = t1 * (1.0f / 64.0f);
        float dv2 = acc2 - mu;
        float t2 = dv2 * dv2;
        #pragma unroll
        for (int m = 1; m < 64; m <<= 1) t2 += __shfl_xor(t2, m, 64);
        float xnew = dv2 * rsqrtf(t2 * (1.0f / 64.0f) + EPS) *
                     p.fln_g[layer * 64 + c] + p.fln_b[layer * 64 + c];
        __syncthreads();          // WB/xrow reads complete
        xrow[rl][c] = xnew;
        if (layer < 3) {
            // restage ST = Ws[layer] into WB (stride 68; FT dead after fin)
            const float4* sw = (const float4*)(p.Ws + layer * 4096);
            #pragma unroll
            for (int s = 0; s < 4; ++s) {
                int i = tid + s * 256;
                float4 w = sw[i];
                int cc = i >> 4, u = i & 15;
                *(float4*)(WB + cc * 68 + 4 * ((u + 2 * cc) & 15)) = w;
            }
        }
        __syncthreads();

        if (tid < 64) {
            float mn = 1e30f, off = -1e30f, dg = -1e30f;
            #pragma unroll
            for (int r2 = 0; r2 < 4; ++r2) {
                float v = xrow[r2][tid];
                mn = fminf(mn, v);
                if (x0 + (r2 >> 1) == y0 + (r2 & 1)) dg = fmaxf(dg, v);
                else off = fmaxf(off, v);
            }
            pool_atomic(p, layer, b_blk, tid, mn, off, dg);
        }

        if (layer < 3) {
            float acc = p.bs[layer * 64 + c];
            #pragma unroll
            for (int u = 0; u < 16; ++u) {
                float4 w = *(const float4*)(WB + c * 68 + 4 * ((u + 2 * c) & 15));
                float4 xr = *(const float4*)(&xrow[rl][4 * u]);
                acc = fmaf(w.x, xr.x, acc); acc = fmaf(w.y, xr.y, acc);
                acc = fmaf(w.z, xr.z, acc); acc = fmaf(w.w, xr.w, acc);
            }
            int x = x0 + rx, y = y0 + ry;
            AG_STORE(&hout[(b_blk * 1024 + x * 32 + y) * 64 + c], acc);
            AG_STORE(&houtT[((b_blk * 32 + y) * 32 + x) * 64 + c], acc);
            gridbar(p.bar, layer, blk);
        }
    }

    // ---- tail-block pattern: 512th arriver runs the epilogue ----
    __syncthreads();   // vmcnt(0) drains the pool atomics
    if (tid == 0) {
        int r = __hip_atomic_fetch_add(&p.bar[480], 1, __ATOMIC_RELAXED,
                                       __HIP_MEMORY_SCOPE_AGENT);
        tailflag = (r == 511) ? 1 : 0;
    }
    __syncthreads();
    if (!tailflag) return;

    // ================= EPILOGUE (tail block only) =================
    #pragma unroll
    for (int s = 0; s < 2; ++s) {
        int slot = tid + s * 256;
        unsigned ud = AG_LOAD(&p.PdgU[slot]);
        unsigned uo = AG_LOAD(&p.PoffU[slot]);
        unsigned um = AG_LOAD(&p.PmnU[slot]);
        sm_dg[slot]  = fdec(ud);
        sm_off[slot] = fdec(uo);
        sm_mn[slot]  = -fdec(um);
    }
    __syncthreads();
    if (tid < 4) {
        float gmx = -1e30f, gmn = 1e30f;
        for (int i2 = 0; i2 < 128; ++i2) {
            gmx = fmaxf(gmx, sm_dg[tid * 128 + i2]);
            gmn = fminf(gmn, sm_mn[tid * 128 + i2]);
        }
        vals[tid] = fabsf(gmx - gmn);
    }
    __syncthreads();
    {
        int bb = tid >> 7, cc = (tid >> 2) & 31, pp = tid & 3;
        float a2 = 0.0f;
        for (int l = 0; l < 4; ++l) {
            float val = vals[l];
            const float* Wr = p.opW + l * 4096 + cc * 128;
            int base = l * 128 + bb * 64;
            for (int j = pp * 32; j < pp * 32 + 32; ++j) {
                float pv;
                if (j < 64) pv = sm_dg[base + j];
                else        pv = fmaxf(sm_off[base + j - 64], sm_dg[base + j - 64] - val);
                a2 = fmaf(Wr[j], pv, a2);
            }
        }
        psum[tid] = a2;
    }
    __syncthreads();
    if (tid < 64) {
        int bb = tid >> 5, cc = tid & 31;
        float a2 = 0.0f;
        for (int l = 0; l < 4; ++l) a2 += p.opb[l * 32 + cc];
        for (int pp = 0; pp < 4; ++pp) a2 += psum[bb * 128 + cc * 4 + pp];
        scores_s[tid] = a2;
    }
    __syncthreads();
    if (tid < 32) {
        float sA = scores_s[tid], sB = scores_s[32 + tid];
        float mu2 = 0.5f * (sA + sB);
        float va = 0.5f * ((sA - mu2) * (sA - mu2) + (sB - mu2) * (sB - mu2));
        float inv = rsqrtf(va + EPS);
        p.out[tid]      = (sA - mu2) * inv;
        p.out[32 + tid] = (sB - mu2) * inv;
    }
}

// ---------------------------------------------------------------------------
extern "C" void kernel_launch(void* const* d_in, const int* in_sizes, int n_in,
                              void* d_out, int out_size, void* d_ws, size_t ws_size,
                              hipStream_t stream) {
    Params prm;
    prm.ei    = (const int*)d_in[0];
    prm.batch = (const int*)d_in[1];
    prm.E     = in_sizes[0] / 2;
    prm.W0    = (const float*)d_in[2];
    prm.b0    = (const float*)d_in[3];
    prm.Ws    = (const float*)d_in[4];
    prm.bs    = (const float*)d_in[5];
    prm.ln_g  = (const float*)d_in[6];
    prm.ln_b  = (const float*)d_in[7];
    prm.fW0   = (const float*)d_in[8];
    prm.fb0   = (const float*)d_in[9];
    prm.fWs   = (const float*)d_in[10];
    prm.fbs   = (const float*)d_in[11];
    prm.fln_g = (const float*)d_in[12];
    prm.fln_b = (const float*)d_in[13];
    prm.opW   = (const float*)d_in[14];
    prm.opb   = (const float*)d_in[15];

    float* ws = (float*)d_ws;
    prm.hA    = ws;                     // 131072 each, one buffer per layer-edge
    prm.hAT   = prm.hA  + 131072;
    prm.hB    = prm.hAT + 131072;
    prm.hBT   = prm.hB  + 131072;
    prm.hC    = prm.hBT + 131072;
    prm.hCT   = prm.hC  + 131072;
    unsigned* pu = (unsigned*)(prm.hCT + 131072);
    prm.PdgU  = pu;                     // [4][2][64] = 512 each
    prm.PoffU = pu + 512;
    prm.PmnU  = pu + 1024;
    prm.bar   = (int*)(pu + 1536);      // 3 phases x 160 + tail @480
    prm.out   = (float*)d_out;
    // ws total: 6*131072 floats + 2048 u32 = 3.01 MB (< proven 3.41 MB bound)

    hipMemsetAsync(pu, 0, 2048 * sizeof(unsigned), stream);
    kfused<<<512, 256, 0, stream>>>(prm);
}

// Round 13
// 156.801 us; speedup vs baseline: 3.5708x; 1.0547x over previous
//
#include <hip/hip_runtime.h>
#include <math.h>

// Shapes fixed by the reference: B=2, N=32, L=4, ED=64, H=4, HD=16
#define EPS 1e-5f

#define AG_LOAD(p)     __hip_atomic_load((p), __ATOMIC_RELAXED, __HIP_MEMORY_SCOPE_AGENT)
#define AG_STORE(p, v) __hip_atomic_store((p), (v), __ATOMIC_RELAXED, __HIP_MEMORY_SCOPE_AGENT)

struct Params {
    const int* ei; const int* batch; int E;
    const float* W0; const float* b0; const float* Ws; const float* bs;
    const float* ln_g; const float* ln_b;
    const float* fW0; const float* fb0; const float* fWs; const float* fbs;
    const float* fln_g; const float* fln_b;
    const float* opW; const float* opb;
    float* hA; float* hAT;   // h + transposed copy hT[b][y][x][c], layers 1/3
    float* hB; float* hBT;   // layer 2
    float* xbuf;             // x rows, block-owned (same block writes & reads)
    float* Pmin; float* Poff; float* Pdg;  // [4 layers][256 blocks][64 e]
    int* bar;                // tail counter (zeroed by k0)
    float* out;              // 64
};

// ---------------------------------------------------------------------------
// K0: adjacency slabs + closed-form layer 0 + pool partial 0 + lin -> h1/h1T.
__launch_bounds__(512, 1)
__global__ void k0(Params p) {
    const int tid  = threadIdx.x;
    const int blk  = blockIdx.x;
    const int gtid = blk * 512 + tid;
    const int c    = tid & 63;
    const int d    = c & 15;
    const int rl   = tid >> 6;
    const int r0     = blk * 8;
    const int b_blk  = r0 >> 10;
    const int xi_blk = (r0 >> 5) & 31;
    const int y0     = r0 & 31;
    const int rld    = xi_blk - y0;
    const int a_l  = c & 31;
    const int h1   = c >> 5;

    __shared__ float xslab[32];
    __shared__ float yslab[256];
    __shared__ __align__(16) float cA[64], cC[64], cW[64], cB0[64], cG[64], cBl[64];
    __shared__ float hstat[3][4];
    __shared__ __align__(16) float pp_s[256 * 68];
    __shared__ float A1_s[8 * 132];
    __shared__ float K0h_s[8][4];
    __shared__ __align__(16) float xrow[8][64];
    __shared__ __align__(16) float xu_s[8][64];
    __shared__ float Wf0[64];
    __shared__ __align__(16) float T65[64 * 68];
    __shared__ __align__(16) float ST[64 * 68];

    if (blk == 0 && tid == 0) p.bar[0] = 0;

    if (tid < 32)  xslab[tid] = 0.0f;
    if (tid < 256) yslab[tid] = 0.0f;

    if (tid < 64) {
        float Wc = p.W0[c], bc = p.b0[c];
        float sW = Wc, sB = bc;
        #pragma unroll
        for (int m = 1; m < 16; m <<= 1) {
            sW += __shfl_xor(sW, m, 16);
            sB += __shfl_xor(sB, m, 16);
        }
        float Ac = Wc - sW * 0.0625f;
        float Bc = bc - sB * 0.0625f;
        float sAA = Ac * Ac, sAB = Ac * Bc, sBB = Bc * Bc;
        #pragma unroll
        for (int m = 1; m < 16; m <<= 1) {
            sAA += __shfl_xor(sAA, m, 16);
            sAB += __shfl_xor(sAB, m, 16);
            sBB += __shfl_xor(sBB, m, 16);
        }
        cA[c] = Ac; cC[c] = Bc; cW[c] = Wc; cB0[c] = bc;
        cG[c] = p.ln_g[d]; cBl[c] = p.ln_b[d];
        if (d == 0) {
            hstat[0][c >> 4] = sAA * 0.0625f;
            hstat[1][c >> 4] = sAB * 0.0625f;
            hstat[2][c >> 4] = sBB * 0.0625f;
        }
        Wf0[tid] = p.fW0[tid * 65];
    }
    for (int i = tid; i < 1024; i += 512) {
        int cc = i >> 4, u = i & 15;
        const float* src = p.fW0 + cc * 65 + 1 + 4 * u;
        float4 w = make_float4(src[0], src[1], src[2], src[3]);
        *(float4*)(T65 + cc * 68 + 4 * ((u + 2 * cc) & 15)) = w;
    }
    for (int i = tid; i < 1024; i += 512) {
        float4 w = ((const float4*)p.Ws)[i];
        int cc = i >> 4, u = i & 15;
        *(float4*)(ST + cc * 68 + 4 * ((u + 2 * cc) & 15)) = w;
    }
    __syncthreads();

    for (int e2 = tid; e2 < p.E; e2 += 512) {
        int e0 = p.ei[e2], e1 = p.ei[p.E + e2];
        int g  = p.batch[e0];
        if (g == b_blk) {
            int ls = e0 - g * 32, ld = e1 - g * 32;
            if (ls == xi_blk) atomicAdd(&xslab[ld], 1.0f);
            unsigned dy = (unsigned)(ld - y0);
            if (dy < 8u) atomicAdd(&yslab[ls * 8 + dy], 1.0f);
        }
    }
    __syncthreads();
    if (tid == 0) xslab[xi_blk] = 2.0f;
    if (tid < 8)  yslab[(y0 + tid) * 8 + tid] = 2.0f;
    __syncthreads();

    const float vx = xslab[a_l];
    const float vy = yslab[a_l * 8 + rl];
    float s0, s1, is0, is1, w0m, w1m;
    {
        const int hh = h1;
        float rsx = rsqrtf(fmaf(fmaf(hstat[0][hh], vx, 2.0f * hstat[1][hh]), vx, hstat[2][hh]) + EPS);
        float rsy = rsqrtf(fmaf(fmaf(hstat[0][hh], vy, 2.0f * hstat[1][hh]), vy, hstat[2][hh]) + EPS);
        float qq = 0.f, sp = 0.f, sq = 0.f;
        #pragma unroll
        for (int t = 0; t < 4; ++t) {
            int dd = hh * 16 + 4 * t;
            float4 av = *(const float4*)(cA + dd);
            float4 bv = *(const float4*)(cC + dd);
            float4 wv = *(const float4*)(cW + dd);
            float4 b0v = *(const float4*)(cB0 + dd);
            float4 gv = *(const float4*)(cG + dd);
            float4 blv = *(const float4*)(cBl + dd);
            float4 ppv;
            float qx, qy;
            qx = fmaf(av.x, vx, bv.x) * rsx * gv.x + blv.x;
            qy = fmaf(av.x, vy, bv.x) * rsy * gv.x + blv.x;
            qq = fmaf(qx, qy, qq);
            ppv.x = fmaf(wv.x, vx, b0v.x) * fmaf(wv.x, vy, b0v.x);
            qx = fmaf(av.y, vx, bv.y) * rsx * gv.y + blv.y;
            qy = fmaf(av.y, vy, bv.y) * rsy * gv.y + blv.y;
            qq = fmaf(qx, qy, qq);
            ppv.y = fmaf(wv.y, vx, b0v.y) * fmaf(wv.y, vy, b0v.y);
            qx = fmaf(av.z, vx, bv.z) * rsx * gv.z + blv.z;
            qy = fmaf(av.z, vy, bv.z) * rsy * gv.z + blv.z;
            qq = fmaf(qx, qy, qq);
            ppv.z = fmaf(wv.z, vx, b0v.z) * fmaf(wv.z, vy, b0v.z);
            qx = fmaf(av.w, vx, bv.w) * rsx * gv.w + blv.w;
            qy = fmaf(av.w, vy, bv.w) * rsy * gv.w + blv.w;
            qq = fmaf(qx, qy, qq);
            ppv.w = fmaf(wv.w, vx, b0v.w) * fmaf(wv.w, vy, b0v.w);
            sp += ppv.x + ppv.y + ppv.z + ppv.w;
            sq += ppv.x*ppv.x + ppv.y*ppv.y + ppv.z*ppv.z + ppv.w*ppv.w;
            *(float4*)(pp_s + (a_l * 8 + rl) * 68 + 4 * (((hh * 4 + t) + 3 * a_l) & 15)) = ppv;
        }
        s0 = qq * 0.25f;
        float mu = sp * 0.0625f, var = fmaxf(sq * 0.0625f - mu * mu, 0.f);
        is0 = rsqrtf(var + EPS); w0m = mu * is0;
    }
    {
        const int hh = h1 + 2;
        float rsx = rsqrtf(fmaf(fmaf(hstat[0][hh], vx, 2.0f * hstat[1][hh]), vx, hstat[2][hh]) + EPS);
        float rsy = rsqrtf(fmaf(fmaf(hstat[0][hh], vy, 2.0f * hstat[1][hh]), vy, hstat[2][hh]) + EPS);
        float qq = 0.f, sp = 0.f, sq = 0.f;
        #pragma unroll
        for (int t = 0; t < 4; ++t) {
            int dd = hh * 16 + 4 * t;
            float4 av = *(const float4*)(cA + dd);
            float4 bv = *(const float4*)(cC + dd);
            float4 wv = *(const float4*)(cW + dd);
            float4 b0v = *(const float4*)(cB0 + dd);
            float4 gv = *(const float4*)(cG + dd);
            float4 blv = *(const float4*)(cBl + dd);
            float4 ppv;
            float qx, qy;
            qx = fmaf(av.x, vx, bv.x) * rsx * gv.x + blv.x;
            qy = fmaf(av.x, vy, bv.x) * rsy * gv.x + blv.x;
            qq = fmaf(qx, qy, qq);
            ppv.x = fmaf(wv.x, vx, b0v.x) * fmaf(wv.x, vy, b0v.x);
            qx = fmaf(av.y, vx, bv.y) * rsx * gv.y + blv.y;
            qy = fmaf(av.y, vy, bv.y) * rsy * gv.y + blv.y;
            qq = fmaf(qx, qy, qq);
            ppv.y = fmaf(wv.y, vx, b0v.y) * fmaf(wv.y, vy, b0v.y);
            qx = fmaf(av.z, vx, bv.z) * rsx * gv.z + blv.z;
            qy = fmaf(av.z, vy, bv.z) * rsy * gv.z + blv.z;
            qq = fmaf(qx, qy, qq);
            ppv.z = fmaf(wv.z, vx, b0v.z) * fmaf(wv.z, vy, b0v.z);
            qx = fmaf(av.w, vx, bv.w) * rsx * gv.w + blv.w;
            qy = fmaf(av.w, vy, bv.w) * rsy * gv.w + blv.w;
            qq = fmaf(qx, qy, qq);
            ppv.w = fmaf(wv.w, vx, b0v.w) * fmaf(wv.w, vy, b0v.w);
            sp += ppv.x + ppv.y + ppv.z + ppv.w;
            sq += ppv.x*ppv.x + ppv.y*ppv.y + ppv.z*ppv.z + ppv.w*ppv.w;
            *(float4*)(pp_s + (a_l * 8 + rl) * 68 + 4 * (((hh * 4 + t) + 3 * a_l) & 15)) = ppv;
        }
        s1 = qq * 0.25f;
        float mu = sp * 0.0625f, var = fmaxf(sq * 0.0625f - mu * mu, 0.f);
        is1 = rsqrtf(var + EPS); w1m = mu * is1;
    }

    float m0 = s0, m1 = s1;
    #pragma unroll
    for (int m = 1; m < 32; m <<= 1) {
        m0 = fmaxf(m0, __shfl_xor(m0, m));
        m1 = fmaxf(m1, __shfl_xor(m1, m));
    }
    float e0 = __expf(s0 - m0), e1 = __expf(s1 - m1);
    float l0 = e0, l1 = e1, k0a = e0 * w0m, k1a = e1 * w1m;
    #pragma unroll
    for (int m = 1; m < 32; m <<= 1) {
        l0 += __shfl_xor(l0, m);  l1 += __shfl_xor(l1, m);
        k0a += __shfl_xor(k0a, m); k1a += __shfl_xor(k1a, m);
    }
    A1_s[rl * 132 + h1 * 33 + a_l]       = e0 * is0 / l0;
    A1_s[rl * 132 + (h1 + 2) * 33 + a_l] = e1 * is1 / l1;
    if (a_l == 0) {
        K0h_s[rl][h1]     = k0a / l0;
        K0h_s[rl][h1 + 2] = k1a / l1;
    }

    {
        const int hc = c >> 4;
        float acc = 0.f;
        #pragma unroll
        for (int a = 0; a < 32; ++a) {
            float pv = pp_s[(a * 8 + rl) * 68 + 4 * (((c >> 2) + 3 * a) & 15) + (c & 3)];
            acc = fmaf(A1_s[rl * 132 + hc * 33 + a], pv, acc);
        }
        xu_s[rl][c] = (acc - K0h_s[rl][hc]) * cG[c] + cBl[c];
    }

    const float adjv = xslab[y0 + rl];
    float acc2 = fmaf(Wf0[c], adjv, p.fb0[c]);
    #pragma unroll
    for (int u = 0; u < 16; ++u) {
        float4 w = *(const float4*)(T65 + c * 68 + 4 * ((u + 2 * c) & 15));
        float4 xr = *(const float4*)(&xu_s[rl][4 * u]);
        acc2 = fmaf(w.x, xr.x, acc2); acc2 = fmaf(w.y, xr.y, acc2);
        acc2 = fmaf(w.z, xr.z, acc2); acc2 = fmaf(w.w, xr.w, acc2);
    }
    float t1 = acc2;
    #pragma unroll
    for (int m = 1; m < 64; m <<= 1) t1 += __shfl_xor(t1, m, 64);
    float mu = t1 * (1.0f / 64.0f);
    float dv2 = acc2 - mu;
    float t2 = dv2 * dv2;
    #pragma unroll
    for (int m = 1; m < 64; m <<= 1) t2 += __shfl_xor(t2, m, 64);
    float xnew = dv2 * rsqrtf(t2 * (1.0f / 64.0f) + EPS) * p.fln_g[c] + p.fln_b[c];
    xrow[rl][c]  = xnew;
    p.xbuf[gtid] = xnew;
    __syncthreads();

    if (tid < 64) {
        float mn = 1e30f, off = -1e30f, dg = -1e30f;
        #pragma unroll
        for (int r2 = 0; r2 < 8; ++r2) {
            float v = xrow[r2][tid];
            mn = fminf(mn, v);
            if (r2 == rld) dg = v; else off = fmaxf(off, v);
        }
        int o = blk * 64 + tid;
        p.Pmin[o] = mn; p.Poff[o] = off; p.Pdg[o] = dg;
    }

    // lin layer 1: h + transposed copy (q derived in klayer)
    {
        float acc = p.bs[c];
        #pragma unroll
        for (int u = 0; u < 16; ++u) {
            float4 w = *(const float4*)(ST + c * 68 + 4 * ((u + 2 * c) & 15));
            float4 xr = *(const float4*)(&xrow[rl][4 * u]);
            acc = fmaf(w.x, xr.x, acc); acc = fmaf(w.y, xr.y, acc);
            acc = fmaf(w.z, xr.z, acc); acc = fmaf(w.w, xr.w, acc);
        }
        p.hA[gtid] = acc;
        p.hAT[((b_blk * 32 + y0 + rl) * 32 + xi_blk) * 64 + c] = acc;
    }
}

// ---------------------------------------------------------------------------
__launch_bounds__(512, 1)
__global__ void klayer(Params p, int layer, int is_last) {
    const int tid  = threadIdx.x;
    const int blk  = blockIdx.x;
    const int gtid = blk * 512 + tid;
    const int c    = tid & 63;
    const int d    = c & 15;
    const int rl   = tid >> 6;
    const int r0     = blk * 8;
    const int b_blk  = r0 >> 10;
    const int xi_blk = (r0 >> 5) & 31;
    const int y0     = r0 & 31;
    const int rld    = xi_blk - y0;
    const int slab_off = (b_blk * 1024 + xi_blk * 32) * 64;
    const int a_l  = c & 31;
    const int h1   = c >> 5;

    const float* hin  = (layer == 2) ? p.hB  : p.hA;
    const float* hinT = (layer == 2) ? p.hBT : p.hAT;
    float* hout  = (layer == 1) ? p.hB  : p.hA;
    float* houtT = (layer == 1) ? p.hBT : p.hAT;

    __shared__ __align__(16) float hx_s[32 * 68];
    __shared__ __align__(16) float yT_s[256 * 68];   // hT[b, y0+rl2, a, :] rotated
    __shared__ float A1_s[8 * 132];
    __shared__ float K0h_s[8][4];
    __shared__ __align__(16) float xrow[8][64];
    __shared__ __align__(16) float xu_s[8][64];
    __shared__ __align__(16) float FT[64 * 132];
    __shared__ __align__(16) float ST[64 * 68];
    __shared__ __align__(16) float g16[16], b16[16];
    __shared__ float vals[4];
    __shared__ float scores_s[64];
    __shared__ int tailflag;
    float* sm_mn  = yT_s;          // tail-only overlays (yT_s dead by then)
    float* sm_off = yT_s + 512;
    float* sm_dg  = yT_s + 1024;
    float* psum   = yT_s + 1536;

    // ---- staging: ALL global reads fully coalesced ----
    float xv = p.xbuf[gtid];
    // y-side: contiguous 64 KB = hT[b_blk][y0..y0+7][*][:]
    {
        const float4* src = (const float4*)(hinT + (b_blk * 32 + y0) * 2048);
        #pragma unroll
        for (int k = 0; k < 8; ++k) {
            int i = tid + k * 512;
            float4 v = src[i];
            int rl2 = i >> 9, a = (i >> 4) & 31, u = i & 15;
            *(float4*)(yT_s + (rl2 * 32 + a) * 68 + 4 * ((u + 2 * a) & 15)) = v;
        }
    }
    // x-slab: contiguous 8 KB
    {
        float4 hsl = ((const float4*)(hin + slab_off))[tid];
        int a = tid >> 4, t = tid & 15, pr = (t + 2 * a) & 15;
        *(float4*)(hx_s + a * 68 + 4 * pr) = hsl;
    }
    if (tid < 16) {
        g16[tid] = p.ln_g[layer * 16 + tid];
        b16[tid] = p.ln_b[layer * 16 + tid];
    }
    {
        const float* fw = p.fWs + (layer - 1) * 8192;
        for (int i = tid; i < 2048; i += 512) {
            float4 w = ((const float4*)fw)[i];
            int cc = i >> 5, u = i & 31;
            *(float4*)(FT + cc * 132 + 4 * ((u + 2 * cc) & 31)) = w;
        }
    }
    if (!is_last) {
        const float* sw = p.Ws + layer * 4096;
        for (int i = tid; i < 1024; i += 512) {
            float4 w = ((const float4*)sw)[i];
            int cc = i >> 4, u = i & 15;
            *(float4*)(ST + cc * 68 + 4 * ((u + 2 * cc) & 15)) = w;
        }
    }
    xrow[rl][c] = xv;
    __syncthreads();

    // ---- pass1: per (a, h) serial dots; q = LN16(h) in-lane; both sides LDS ----
    float s0, s1, is0, is1, w0m, w1m;
    {
        const int hh = h1;
        float4 xh4[4], yh4[4];
        float sxp = 0.f, sxq = 0.f, syp = 0.f, syq = 0.f;
        #pragma unroll
        for (int t = 0; t < 4; ++t) {
            int ps = 4 * (((hh * 4 + t) + 2 * a_l) & 15);
            float4 v = *(const float4*)(hx_s + a_l * 68 + ps);
            float4 y = *(const float4*)(yT_s + (rl * 32 + a_l) * 68 + ps);
            xh4[t] = v; yh4[t] = y;
            sxp += v.x + v.y + v.z + v.w;
            sxq += v.x*v.x + v.y*v.y + v.z*v.z + v.w*v.w;
            syp += y.x + y.y + y.z + y.w;
            syq += y.x*y.x + y.y*y.y + y.z*y.z + y.w*y.w;
        }
        float mxm = sxp * 0.0625f;
        float rsx = rsqrtf(fmaxf(sxq * 0.0625f - mxm * mxm, 0.f) + EPS);
        float mym = syp * 0.0625f;
        float rsy = rsqrtf(fmaxf(syq * 0.0625f - mym * mym, 0.f) + EPS);
        float qq = 0.f, sp = 0.f, sq = 0.f;
        #pragma unroll
        for (int t = 0; t < 4; ++t) {
            float4 g4 = *(const float4*)(g16 + 4 * t);
            float4 b4 = *(const float4*)(b16 + 4 * t);
            float4 xh = xh4[t], yh = yh4[t];
            float4 ppv;
            float qx, qy;
            qx = (xh.x - mxm) * rsx * g4.x + b4.x;
            qy = (yh.x - mym) * rsy * g4.x + b4.x;
            qq = fmaf(qx, qy, qq);  ppv.x = xh.x * yh.x;
            qx = (xh.y - mxm) * rsx * g4.y + b4.y;
            qy = (yh.y - mym) * rsy * g4.y + b4.y;
            qq = fmaf(qx, qy, qq);  ppv.y = xh.y * yh.y;
            qx = (xh.z - mxm) * rsx * g4.z + b4.z;
            qy = (yh.z - mym) * rsy * g4.z + b4.z;
            qq = fmaf(qx, qy, qq);  ppv.z = xh.z * yh.z;
            qx = (xh.w - mxm) * rsx * g4.w + b4.w;
            qy = (yh.w - mym) * rsy * g4.w + b4.w;
            qq = fmaf(qx, qy, qq);  ppv.w = xh.w * yh.w;
            sp += ppv.x + ppv.y + ppv.z + ppv.w;
            sq += ppv.x*ppv.x + ppv.y*ppv.y + ppv.z*ppv.z + ppv.w*ppv.w;
        }
        s0 = qq * 0.25f;
        float mu = sp * 0.0625f, var = fmaxf(sq * 0.0625f - mu * mu, 0.f);
        is0 = rsqrtf(var + EPS); w0m = mu * is0;
    }
    {
        const int hh = h1 + 2;
        float4 xh4[4], yh4[4];
        float sxp = 0.f, sxq = 0.f, syp = 0.f, syq = 0.f;
        #pragma unroll
        for (int t = 0; t < 4; ++t) {
            int ps = 4 * (((hh * 4 + t) + 2 * a_l) & 15);
            float4 v = *(const float4*)(hx_s + a_l * 68 + ps);
            float4 y = *(const float4*)(yT_s + (rl * 32 + a_l) * 68 + ps);
            xh4[t] = v; yh4[t] = y;
            sxp += v.x + v.y + v.z + v.w;
            sxq += v.x*v.x + v.y*v.y + v.z*v.z + v.w*v.w;
            syp += y.x + y.y + y.z + y.w;
            syq += y.x*y.x + y.y*y.y + y.z*y.z + y.w*y.w;
        }
        float mxm = sxp * 0.0625f;
        float rsx = rsqrtf(fmaxf(sxq * 0.0625f - mxm * mxm, 0.f) + EPS);
        float mym = syp * 0.0625f;
        float rsy = rsqrtf(fmaxf(syq * 0.0625f - mym * mym, 0.f) + EPS);
        float qq = 0.f, sp = 0.f, sq = 0.f;
        #pragma unroll
        for (int t = 0; t < 4; ++t) {
            float4 g4 = *(const float4*)(g16 + 4 * t);
            float4 b4 = *(const float4*)(b16 + 4 * t);
            float4 xh = xh4[t], yh = yh4[t];
            float4 ppv;
            float qx, qy;
            qx = (xh.x - mxm) * rsx * g4.x + b4.x;
            qy = (yh.x - mym) * rsy * g4.x + b4.x;
            qq = fmaf(qx, qy, qq);  ppv.x = xh.x * yh.x;
            qx = (xh.y - mxm) * rsx * g4.y + b4.y;
            qy = (yh.y - mym) * rsy * g4.y + b4.y;
            qq = fmaf(qx, qy, qq);  ppv.y = xh.y * yh.y;
            qx = (xh.z - mxm) * rsx * g4.z + b4.z;
            qy = (yh.z - mym) * rsy * g4.z + b4.z;
            qq = fmaf(qx, qy, qq);  ppv.z = xh.z * yh.z;
            qx = (xh.w - mxm) * rsx * g4.w + b4.w;
            qy = (yh.w - mym) * rsy * g4.w + b4.w;
            qq = fmaf(qx, qy, qq);  ppv.w = xh.w * yh.w;
            sp += ppv.x + ppv.y + ppv.z + ppv.w;
            sq += ppv.x*ppv.x + ppv.y*ppv.y + ppv.z*ppv.z + ppv.w*ppv.w;
        }
        s1 = qq * 0.25f;
        float mu = sp * 0.0625f, var = fmaxf(sq * 0.0625f - mu * mu, 0.f);
        is1 = rsqrtf(var + EPS); w1m = mu * is1;
    }

    // ---- single softmax reduction per row ----
    float m0 = s0, m1 = s1;
    #pragma unroll
    for (int m = 1; m < 32; m <<= 1) {
        m0 = fmaxf(m0, __shfl_xor(m0, m));
        m1 = fmaxf(m1, __shfl_xor(m1, m));
    }
    float e0 = __expf(s0 - m0), e1 = __expf(s1 - m1);
    float l0 = e0, l1 = e1, k0a = e0 * w0m, k1a = e1 * w1m;
    #pragma unroll
    for (int m = 1; m < 32; m <<= 1) {
        l0 += __shfl_xor(l0, m);  l1 += __shfl_xor(l1, m);
        k0a += __shfl_xor(k0a, m); k1a += __shfl_xor(k1a, m);
    }
    A1_s[rl * 132 + h1 * 33 + a_l]       = e0 * is0 / l0;
    A1_s[rl * 132 + (h1 + 2) * 33 + a_l] = e1 * is1 / l1;
    if (a_l == 0) {
        K0h_s[rl][h1]     = k0a / l0;
        K0h_s[rl][h1 + 2] = k1a / l1;
    }

    // ---- pass2: recompute products from LDS (no pp_s) ----
    {
        const int hc = c >> 4;
        const int ce = c & 3;
        float acc = 0.f;
        #pragma unroll
        for (int a = 0; a < 32; ++a) {
            int ps = 4 * (((c >> 2) + 2 * a) & 15) + ce;
            float hxv = hx_s[a * 68 + ps];
            float hyv = yT_s[(rl * 32 + a) * 68 + ps];
            acc = fmaf(A1_s[rl * 132 + hc * 33 + a], hxv * hyv, acc);
        }
        xu_s[rl][c] = (acc - K0h_s[rl][hc]) * g16[d] + b16[d];
    }

    // ---- fin + LN64 ----
    float acc2 = p.fbs[(layer - 1) * 64 + c];
    #pragma unroll
    for (int u = 0; u < 16; ++u) {
        float4 w = *(const float4*)(FT + c * 132 + 4 * ((u + 2 * c) & 31));
        float4 xr = *(const float4*)(&xrow[rl][4 * u]);
        acc2 = fmaf(w.x, xr.x, acc2); acc2 = fmaf(w.y, xr.y, acc2);
        acc2 = fmaf(w.z, xr.z, acc2); acc2 = fmaf(w.w, xr.w, acc2);
    }
    #pragma unroll
    for (int u = 16; u < 32; ++u) {
        float4 w = *(const float4*)(FT + c * 132 + 4 * ((u + 2 * c) & 31));
        float4 xr = *(const float4*)(&xu_s[rl][4 * (u - 16)]);
        acc2 = fmaf(w.x, xr.x, acc2); acc2 = fmaf(w.y, xr.y, acc2);
        acc2 = fmaf(w.z, xr.z, acc2); acc2 = fmaf(w.w, xr.w, acc2);
    }
    float t1 = acc2;
    #pragma unroll
    for (int m = 1; m < 64; m <<= 1) t1 += __shfl_xor(t1, m, 64);
    float mu = t1 * (1.0f / 64.0f);
    float dv2 = acc2 - mu;
    float t2 = dv2 * dv2;
    #pragma unroll
    for (int m = 1; m < 64; m <<= 1) t2 += __shfl_xor(t2, m, 64);
    float xnew = dv2 * rsqrtf(t2 * (1.0f / 64.0f) + EPS) *
                 p.fln_g[layer * 64 + c] + p.fln_b[layer * 64 + c];
    __syncthreads();          // xrow reuse hazard
    xrow[rl][c] = xnew;
    if (!is_last) p.xbuf[gtid] = xnew;
    __syncthreads();

    // ---- pool partial ----
    if (tid < 64) {
        float mn = 1e30f, off = -1e30f, dg = -1e30f;
        #pragma unroll
        for (int r2 = 0; r2 < 8; ++r2) {
            float v = xrow[r2][tid];
            mn = fminf(mn, v);
            if (r2 == rld) dg = v; else off = fmaxf(off, v);
        }
        int o = layer * 16384 + blk * 64 + tid;
        if (is_last) {
            AG_STORE(&p.Pmin[o], mn); AG_STORE(&p.Poff[o], off); AG_STORE(&p.Pdg[o], dg);
        } else {
            p.Pmin[o] = mn; p.Poff[o] = off; p.Pdg[o] = dg;
        }
    }

    if (!is_last) {
        float acc = p.bs[layer * 64 + c];
        #pragma unroll
        for (int u = 0; u < 16; ++u) {
            float4 w = *(const float4*)(ST + c * 68 + 4 * ((u + 2 * c) & 15));
            float4 xr = *(const float4*)(&xrow[rl][4 * u]);
            acc = fmaf(w.x, xr.x, acc); acc = fmaf(w.y, xr.y, acc);
            acc = fmaf(w.z, xr.z, acc); acc = fmaf(w.w, xr.w, acc);
        }
        hout[gtid] = acc;
        houtT[((b_blk * 32 + y0 + rl) * 32 + xi_blk) * 64 + c] = acc;
        return;
    }

    // ---- tail-block pattern ----
    __syncthreads();
    if (tid == 0) {
        int r = __hip_atomic_fetch_add(p.bar, 1, __ATOMIC_RELAXED,
                                       __HIP_MEMORY_SCOPE_AGENT);
        tailflag = (r == 255) ? 1 : 0;
    }
    __syncthreads();
    if (!tailflag) return;

    // ================= epilogue (tail block only) =================
    {
        int l = tid >> 7, bb = (tid >> 6) & 1, e = tid & 63;
        float mn = 1e30f, off = -1e30f, dg = -1e30f;
        #pragma unroll 4
        for (int k = 0; k < 128; ++k) {
            int o = l * 16384 + (bb * 128 + k) * 64 + e;
            float vmn, voff, vdg;
            if (l == 3) { vmn = AG_LOAD(&p.Pmin[o]); voff = AG_LOAD(&p.Poff[o]); vdg = AG_LOAD(&p.Pdg[o]); }
            else        { vmn = p.Pmin[o];           voff = p.Poff[o];           vdg = p.Pdg[o]; }
            mn  = fminf(mn,  vmn);
            off = fmaxf(off, voff);
            dg  = fmaxf(dg,  vdg);
        }
        sm_mn[tid] = mn; sm_off[tid] = off; sm_dg[tid] = dg;
    }
    __syncthreads();
    if (tid < 4) {
        float gmx = -1e30f, gmn = 1e30f;
        for (int i2 = 0; i2 < 128; ++i2) {
            gmx = fmaxf(gmx, sm_dg[tid * 128 + i2]);
            gmn = fminf(gmn, sm_mn[tid * 128 + i2]);
        }
        vals[tid] = fabsf(gmx - gmn);
    }
    __syncthreads();
    {
        int bb = tid >> 8, cc = (tid >> 3) & 31, pp = tid & 7;
        float a2 = 0.0f;
        for (int l = 0; l < 4; ++l) {
            float val = vals[l];
            const float* Wr = p.opW + l * 4096 + cc * 128;
            int base = l * 128 + bb * 64;
            for (int j = pp * 16; j < pp * 16 + 16; ++j) {
                float pv;
                if (j < 64) pv = sm_dg[base + j];
                else        pv = fmaxf(sm_off[base + j - 64], sm_dg[base + j - 64] - val);
                a2 = fmaf(Wr[j], pv, a2);
            }
        }
        psum[tid] = a2;
    }
    __syncthreads();
    if (tid < 64) {
        int bb = tid >> 5, cc = tid & 31;
        float a2 = 0.0f;
        for (int l = 0; l < 4; ++l) a2 += p.opb[l * 32 + cc];
        for (int pp = 0; pp < 8; ++pp) a2 += psum[bb * 256 + cc * 8 + pp];
        scores_s[tid] = a2;
    }
    __syncthreads();
    if (tid < 32) {
        float sA = scores_s[tid], sB = scores_s[32 + tid];
        float mu2 = 0.5f * (sA + sB);
        float va = 0.5f * ((sA - mu2) * (sA - mu2) + (sB - mu2) * (sB - mu2));
        float inv = rsqrtf(va + EPS);
        p.out[tid]      = (sA - mu2) * inv;
        p.out[32 + tid] = (sB - mu2) * inv;
    }
}

// ---------------------------------------------------------------------------
extern "C" void kernel_launch(void* const* d_in, const int* in_sizes, int n_in,
                              void* d_out, int out_size, void* d_ws, size_t ws_size,
                              hipStream_t stream) {
    Params prm;
    prm.ei    = (const int*)d_in[0];
    prm.batch = (const int*)d_in[1];
    prm.E     = in_sizes[0] / 2;
    prm.W0    = (const float*)d_in[2];
    prm.b0    = (const float*)d_in[3];
    prm.Ws    = (const float*)d_in[4];
    prm.bs    = (const float*)d_in[5];
    prm.ln_g  = (const float*)d_in[6];
    prm.ln_b  = (const float*)d_in[7];
    prm.fW0   = (const float*)d_in[8];
    prm.fb0   = (const float*)d_in[9];
    prm.fWs   = (const float*)d_in[10];
    prm.fbs   = (const float*)d_in[11];
    prm.fln_g = (const float*)d_in[12];
    prm.fln_b = (const float*)d_in[13];
    prm.opW   = (const float*)d_in[14];
    prm.opb   = (const float*)d_in[15];

    float* ws = (float*)d_ws;
    prm.hA    = ws;
    prm.hAT   = prm.hA   + 131072;
    prm.hB    = prm.hAT  + 131072;
    prm.hBT   = prm.hB   + 131072;
    prm.xbuf  = prm.hBT  + 131072;
    prm.Pmin  = prm.xbuf + 131072;
    prm.Poff  = prm.Pmin + 65536;
    prm.Pdg   = prm.Poff + 65536;
    prm.bar   = (int*)(prm.Pdg + 65536);
    prm.out   = (float*)d_out;

    k0<<<256, 512, 0, stream>>>(prm);
    klayer<<<256, 512, 0, stream>>>(prm, 1, 0);
    klayer<<<256, 512, 0, stream>>>(prm, 2, 0);
    klayer<<<256, 512, 0, stream>>>(prm, 3, 1);
}